// Round 9
// baseline (4275.006 us; speedup 1.0000x reference)
//
#include <hip/hip_runtime.h>

// GraphLSTM v5: recompute split, NO grid sync, NO persistent-kernel tricks.
// A) k_graph_all: graph LSTM all 32 steps, gh/gc in regs (24 persistent),
//    writes per-step per-block partial sums of gh only.
// B) k_bias: 32 blocks -> bias_all[32][256] (S@Wfold2 folded, f32).
// C) k_cell_all: RECOMPUTES graph recurrence (bit-identical bf16 path, so
//    gh(t) is in-register as the cell MFMA A-fragment), carries ch/cc in regs
//    all 32 steps, outputs via 2 MFMAs vs padded Wout^T. No barriers at all.
// Round-6/7/8 lessons: no grid-wide sync (L2 poison), keep persistent regs
// small enough that any allocator choice >=~110 VGPR has no spills.

#define Sx    32
#define Nx    65536
#define OUTx  5
#define KG    96              // graph gates K: [gemb(32) | gh(64)]
#define KC    160             // cell gates K:  [dyn(32) | gh(64) | ch(64)]
#define GRIDA 512             // blocks for A and C
#define TPB   512             // 8 waves x 16 nodes = 128 nodes/block

typedef __attribute__((ext_vector_type(4))) float f32x4;
typedef __attribute__((ext_vector_type(8))) short bf16x8;
typedef unsigned short ushort;
typedef unsigned int uint;

__device__ __forceinline__ float sigm(float x) {
    return __frcp_rn(1.f + __expf(-x));
}
__device__ __forceinline__ float tanh_fast(float x) {
    return fmaf(-2.f, __frcp_rn(1.f + __expf(2.f * x)), 1.f);
}
__device__ __forceinline__ ushort f2b(float x) {
    uint u = __float_as_uint(x);
    u += 0x7fffu + ((u >> 16) & 1u);   // RNE
    return (ushort)(u >> 16);
}

// ---------------- weight prep (once per launch, parallel) ----------------
__global__ __launch_bounds__(256) void k_prep(
    const float* __restrict__ Wih_g, const float* __restrict__ Whh_g,
    const float* __restrict__ bih_g, const float* __restrict__ bhh_g,
    const float* __restrict__ wgr,
    const float* __restrict__ Wih_c, const float* __restrict__ Whh_c,
    const float* __restrict__ bih_c, const float* __restrict__ bhh_c,
    const float* __restrict__ Wout,
    ushort* __restrict__ Wg, ushort* __restrict__ Wc,
    ushort* __restrict__ WoB,
    float* __restrict__ Wfold2,
    float* __restrict__ bsum_g, float* __restrict__ bC0)
{
    const int tid = blockIdx.x * 256 + threadIdx.x;
    const int nt = gridDim.x * 256;
    for (int idx = tid; idx < 256 * KG; idx += nt) {
        int col = idx / KG, k = idx % KG;
        float v = (k < 32) ? Wih_g[col * 32 + k] : Whh_g[col * 64 + (k - 32)];
        Wg[idx] = f2b(v);
    }
    for (int idx = tid; idx < 256 * KC; idx += nt) {
        int col = idx / KC, k = idx % KC;
        float v;
        if (k < 32) v = Wih_c[col * 64 + k];
        else if (k < 96) {
            int d = k - 32; float a = 0.f;
            for (int j = 0; j < 32; ++j)
                a = fmaf(wgr[d * 32 + j], Wih_c[col * 64 + 32 + j], a);
            v = -a;   // per-node part of loo is (-gh)
        } else v = Whh_c[col * 64 + (k - 96)];
        Wc[idx] = f2b(v);
    }
    // WoB[col][k] = Wout^T padded to 16 cols (cols 5..15 zero), bf16
    for (int idx = tid; idx < 16 * 64; idx += nt) {
        int col = idx >> 6, k = idx & 63;
        WoB[idx] = (col < OUTx) ? f2b(Wout[col * 64 + k]) : (ushort)0;
    }
    // Wfold2[k][col] = sum_j wgr[k][j] * Wih_c[col][32+j]   (f32, S-bias path)
    for (int idx = tid; idx < 64 * 256; idx += nt) {
        int k = idx >> 8, col = idx & 255;
        float a = 0.f;
        for (int j = 0; j < 32; ++j)
            a = fmaf(wgr[k * 32 + j], Wih_c[col * 64 + 32 + j], a);
        Wfold2[idx] = a;
    }
    if (tid < 256) {
        bsum_g[tid] = bih_g[tid] + bhh_g[tid];
        bC0[tid]    = bih_c[tid] + bhh_c[tid];
    }
}

// ---------------- A: graph LSTM, all steps, partial sums only -------------
__global__ __launch_bounds__(TPB, 1) void k_graph_all(
    const float* __restrict__ input,               // [S][N][2]
    const float* __restrict__ gh0, const float* __restrict__ gc0,
    const float* __restrict__ Wge, const float* __restrict__ bge,
    const ushort* __restrict__ Wg, const float* __restrict__ bsum_g,
    float* __restrict__ partials,                  // [S][GRIDA][64]
    float* __restrict__ ghf, float* __restrict__ gcf)
{
    const int tid = threadIdx.x;
    const int wave = tid >> 6, lane = tid & 63;
    const int c = lane & 15, g4 = lane >> 4;
    const int nb = blockIdx.x * 128 + wave * 16;
    const int na = nb + c;

    __shared__ __align__(16) ushort t_lds[8][16][72];
    __shared__ float wsum[2][8][64];

    float gcr[4][4];
#pragma unroll
    for (int q = 0; q < 4; ++q)
#pragma unroll
        for (int r = 0; r < 4; ++r)
            gcr[q][r] = gc0[(nb + 4 * g4 + r) * 64 + 16 * q + c];
    bf16x8 agh0, agh1;
#pragma unroll
    for (int j = 0; j < 8; ++j) {
        agh0[j] = (short)f2b(gh0[na * 64 + g4 * 8 + j]);
        agh1[j] = (short)f2b(gh0[na * 64 + 32 + g4 * 8 + j]);
    }

#pragma unroll 1
    for (int t = 0; t < Sx; ++t) {
        const float* frame = input + (size_t)t * Nx * 2;
        const float f0 = frame[2 * na], f1 = frame[2 * na + 1];
        const int lastt = (t == Sx - 1);
        bf16x8 a0;
#pragma unroll
        for (int j = 0; j < 8; ++j) {
            const int k = g4 * 8 + j;
            float v = fmaf(f1, Wge[2 * k + 1], fmaf(f0, Wge[2 * k], bge[k]));
            a0[j] = (short)f2b(fmaxf(v, 0.f));
        }
        float hsq[4];
#pragma unroll
        for (int q = 0; q < 4; ++q) {
            f32x4 acc[4];
#pragma unroll
            for (int g = 0; g < 4; ++g) {
                acc[g] = (f32x4){0.f, 0.f, 0.f, 0.f};
                const ushort* wp = Wg + (16 * (4 * g + q) + c) * KG + g4 * 8;
                bf16x8 b0 = *(const bf16x8*)(wp);
                bf16x8 b1 = *(const bf16x8*)(wp + 32);
                bf16x8 b2 = *(const bf16x8*)(wp + 64);
                acc[g] = __builtin_amdgcn_mfma_f32_16x16x32_bf16(a0,   b0, acc[g], 0, 0, 0);
                acc[g] = __builtin_amdgcn_mfma_f32_16x16x32_bf16(agh0, b1, acc[g], 0, 0, 0);
                acc[g] = __builtin_amdgcn_mfma_f32_16x16x32_bf16(agh1, b2, acc[g], 0, 0, 0);
            }
            const int d = 16 * q + c;
            const float bi = bsum_g[d], bf = bsum_g[64 + d],
                        bg = bsum_g[128 + d], bo = bsum_g[192 + d];
            float s_r = 0.f;
#pragma unroll
            for (int r = 0; r < 4; ++r) {
                const float ai = acc[0][r] + bi, af = acc[1][r] + bf,
                            ag = acc[2][r] + bg, ao = acc[3][r] + bo;
                const float c2 = fmaf(sigm(af), gcr[q][r], sigm(ai) * tanh_fast(ag));
                gcr[q][r] = c2;
                const float h2 = sigm(ao) * tanh_fast(c2);
                t_lds[wave][4 * g4 + r][16 * q + c] = f2b(h2);
                if (lastt) {
                    const int n = nb + 4 * g4 + r;
                    ghf[n * 64 + d] = h2;
                    gcf[n * 64 + d] = c2;
                }
                s_r += h2;
            }
            hsq[q] = s_r;
        }
#pragma unroll
        for (int q = 0; q < 4; ++q) {
            float v = hsq[q];
            v += __shfl_xor(v, 16);
            v += __shfl_xor(v, 32);
            hsq[q] = v;
        }
        if (g4 == 0) {
#pragma unroll
            for (int q = 0; q < 4; ++q) wsum[t & 1][wave][16 * q + c] = hsq[q];
        }
        __syncthreads();
        // transpose read (same-wave dataflow ordering; no barrier needed)
        agh0 = *(const bf16x8*)(&t_lds[wave][c][g4 * 8]);
        agh1 = *(const bf16x8*)(&t_lds[wave][c][32 + g4 * 8]);
        if (tid < 64) {
            float a = 0.f;
#pragma unroll
            for (int w8 = 0; w8 < 8; ++w8) a += wsum[t & 1][w8][tid];
            partials[((size_t)t * GRIDA + blockIdx.x) * 64 + tid] = a;
        }
    }
}

// ---------------- B: per-step bias from partials ---------------------------
__global__ __launch_bounds__(256) void k_bias(
    const float* __restrict__ partials,   // [S][GRIDA][64]
    const float* __restrict__ Wfold2, const float* __restrict__ bC0,
    float* __restrict__ bias_all)         // [S][256]
{
    const int t = blockIdx.x, tid = threadIdx.x;
    __shared__ float red[4][64];
    __shared__ float S[64];
    const int d = tid & 63, j = tid >> 6;
    float a = 0.f;
    for (int b = j; b < GRIDA; b += 4)
        a += partials[((size_t)t * GRIDA + b) * 64 + d];
    red[j][d] = a;
    __syncthreads();
    if (tid < 64) S[tid] = red[0][tid] + red[1][tid] + red[2][tid] + red[3][tid];
    __syncthreads();
    float bv = bC0[tid];
#pragma unroll
    for (int k = 0; k < 64; ++k) bv = fmaf(S[k], Wfold2[k * 256 + tid], bv);
    bias_all[t * 256 + tid] = bv;
}

// ---------------- C: graph recompute + cell LSTM, all steps ----------------
__global__ __launch_bounds__(TPB, 1) void k_cell_all(
    const float* __restrict__ input,               // [S][N][2]
    const float* __restrict__ gh0, const float* __restrict__ gc0,
    const float* __restrict__ ch0, const float* __restrict__ cc0,
    const float* __restrict__ Wge, const float* __restrict__ bge,
    const ushort* __restrict__ Wg, const float* __restrict__ bsum_g,
    const float* __restrict__ Wdy, const float* __restrict__ bdy,
    const ushort* __restrict__ Wc, const float* __restrict__ bias_all,
    const ushort* __restrict__ WoB, const float* __restrict__ bo5,
    float* __restrict__ out0,                      // [S][N][5]
    float* __restrict__ chf, float* __restrict__ ccf)
{
    const int tid = threadIdx.x;
    const int wave = tid >> 6, lane = tid & 63;
    const int c = lane & 15, g4 = lane >> 4;
    const int nb = blockIdx.x * 128 + wave * 16;
    const int na = nb + c;

    __shared__ __align__(16) ushort t_lds[8][16][72];

    float gcr[4][4], ccr[4][4];
#pragma unroll
    for (int q = 0; q < 4; ++q)
#pragma unroll
        for (int r = 0; r < 4; ++r) {
            const int n = nb + 4 * g4 + r, d = 16 * q + c;
            gcr[q][r] = gc0[n * 64 + d];
            ccr[q][r] = cc0[n * 64 + d];
        }
    bf16x8 agh0, agh1, ach0, ach1;
#pragma unroll
    for (int j = 0; j < 8; ++j) {
        agh0[j] = (short)f2b(gh0[na * 64 + g4 * 8 + j]);
        agh1[j] = (short)f2b(gh0[na * 64 + 32 + g4 * 8 + j]);
        ach0[j] = (short)f2b(ch0[na * 64 + g4 * 8 + j]);
        ach1[j] = (short)f2b(ch0[na * 64 + 32 + g4 * 8 + j]);
    }
    // Wout^T fragments (step-invariant)
    bf16x8 woB0 = *(const bf16x8*)(WoB + c * 64 + g4 * 8);
    bf16x8 woB1 = *(const bf16x8*)(WoB + c * 64 + 32 + g4 * 8);
    const float bo_c = (c < OUTx) ? bo5[c] : 0.f;

#pragma unroll 1
    for (int t = 0; t < Sx; ++t) {
        const float* frame = input + (size_t)t * Nx * 2;
        const float f0 = frame[2 * na], f1 = frame[2 * na + 1];
        const int lastt = (t == Sx - 1);

        // ===== graph recompute (bit-identical to k_graph_all) =====
        bf16x8 a0;
#pragma unroll
        for (int j = 0; j < 8; ++j) {
            const int k = g4 * 8 + j;
            float v = fmaf(f1, Wge[2 * k + 1], fmaf(f0, Wge[2 * k], bge[k]));
            a0[j] = (short)f2b(fmaxf(v, 0.f));
        }
#pragma unroll
        for (int q = 0; q < 4; ++q) {
            f32x4 acc[4];
#pragma unroll
            for (int g = 0; g < 4; ++g) {
                acc[g] = (f32x4){0.f, 0.f, 0.f, 0.f};
                const ushort* wp = Wg + (16 * (4 * g + q) + c) * KG + g4 * 8;
                bf16x8 b0 = *(const bf16x8*)(wp);
                bf16x8 b1 = *(const bf16x8*)(wp + 32);
                bf16x8 b2 = *(const bf16x8*)(wp + 64);
                acc[g] = __builtin_amdgcn_mfma_f32_16x16x32_bf16(a0,   b0, acc[g], 0, 0, 0);
                acc[g] = __builtin_amdgcn_mfma_f32_16x16x32_bf16(agh0, b1, acc[g], 0, 0, 0);
                acc[g] = __builtin_amdgcn_mfma_f32_16x16x32_bf16(agh1, b2, acc[g], 0, 0, 0);
            }
            const int d = 16 * q + c;
            const float bi = bsum_g[d], bf = bsum_g[64 + d],
                        bg = bsum_g[128 + d], bo = bsum_g[192 + d];
#pragma unroll
            for (int r = 0; r < 4; ++r) {
                const float ai = acc[0][r] + bi, af = acc[1][r] + bf,
                            ag = acc[2][r] + bg, ao = acc[3][r] + bo;
                const float c2 = fmaf(sigm(af), gcr[q][r], sigm(ai) * tanh_fast(ag));
                gcr[q][r] = c2;
                const float h2 = sigm(ao) * tanh_fast(c2);
                t_lds[wave][4 * g4 + r][16 * q + c] = f2b(h2);
            }
        }
        agh0 = *(const bf16x8*)(&t_lds[wave][c][g4 * 8]);        // gh(t)
        agh1 = *(const bf16x8*)(&t_lds[wave][c][32 + g4 * 8]);

        // ===== cell phase (agh=gh(t), ach=ch(t-1)) =====
        bf16x8 a0c;
#pragma unroll
        for (int j = 0; j < 8; ++j) {
            const int k = g4 * 8 + j;
            float v = fmaf(f1, Wdy[2 * k + 1], fmaf(f0, Wdy[2 * k], bdy[k]));
            a0c[j] = (short)f2b(fmaxf(v, 0.f));
        }
#pragma unroll
        for (int q = 0; q < 4; ++q) {
            f32x4 acc[4];
#pragma unroll
            for (int g = 0; g < 4; ++g) {
                acc[g] = (f32x4){0.f, 0.f, 0.f, 0.f};
                const ushort* wp = Wc + (16 * (4 * g + q) + c) * KC + g4 * 8;
                bf16x8 b0 = *(const bf16x8*)(wp);
                bf16x8 b1 = *(const bf16x8*)(wp + 32);
                bf16x8 b2 = *(const bf16x8*)(wp + 64);
                bf16x8 b3 = *(const bf16x8*)(wp + 96);
                bf16x8 b4 = *(const bf16x8*)(wp + 128);
                acc[g] = __builtin_amdgcn_mfma_f32_16x16x32_bf16(a0c,  b0, acc[g], 0, 0, 0);
                acc[g] = __builtin_amdgcn_mfma_f32_16x16x32_bf16(agh0, b1, acc[g], 0, 0, 0);
                acc[g] = __builtin_amdgcn_mfma_f32_16x16x32_bf16(agh1, b2, acc[g], 0, 0, 0);
                acc[g] = __builtin_amdgcn_mfma_f32_16x16x32_bf16(ach0, b3, acc[g], 0, 0, 0);
                acc[g] = __builtin_amdgcn_mfma_f32_16x16x32_bf16(ach1, b4, acc[g], 0, 0, 0);
            }
            const int d = 16 * q + c;
            const float bi = bias_all[t * 256 + d],
                        bf = bias_all[t * 256 + 64 + d],
                        bg = bias_all[t * 256 + 128 + d],
                        bov = bias_all[t * 256 + 192 + d];
#pragma unroll
            for (int r = 0; r < 4; ++r) {
                const float ai = acc[0][r] + bi, af = acc[1][r] + bf,
                            ag = acc[2][r] + bg, ao = acc[3][r] + bov;
                const float c2 = fmaf(sigm(af), ccr[q][r], sigm(ai) * tanh_fast(ag));
                ccr[q][r] = c2;
                const float h2 = sigm(ao) * tanh_fast(c2);
                t_lds[wave][4 * g4 + r][16 * q + c] = f2b(h2);
                if (lastt) {
                    const int n = nb + 4 * g4 + r;
                    chf[n * 64 + d] = h2;
                    ccf[n * 64 + d] = c2;
                }
            }
        }
        ach0 = *(const bf16x8*)(&t_lds[wave][c][g4 * 8]);        // ch(t)
        ach1 = *(const bf16x8*)(&t_lds[wave][c][32 + g4 * 8]);

        // ===== outputs: out = ch(t) @ Wout^T via 2 MFMAs =====
        {
            f32x4 oa = (f32x4){0.f, 0.f, 0.f, 0.f};
            oa = __builtin_amdgcn_mfma_f32_16x16x32_bf16(ach0, woB0, oa, 0, 0, 0);
            oa = __builtin_amdgcn_mfma_f32_16x16x32_bf16(ach1, woB1, oa, 0, 0, 0);
            if (c < OUTx) {
                float* outp = out0 + (size_t)t * Nx * OUTx;
#pragma unroll
                for (int r = 0; r < 4; ++r)
                    outp[(nb + 4 * g4 + r) * OUTx + c] = oa[r] + bo_c;
            }
        }
    }
}

extern "C" void kernel_launch(void* const* d_in, const int* in_sizes, int n_in,
                              void* d_out, int out_size, void* d_ws, size_t ws_size,
                              hipStream_t stream) {
    const float* input   = (const float*)d_in[0];   // [S][N][2]
    const float* cell_h0 = (const float*)d_in[1];
    const float* cell_c0 = (const float*)d_in[2];
    const float* graph_h0= (const float*)d_in[3];
    const float* graph_c0= (const float*)d_in[4];
    const float* W_dyn   = (const float*)d_in[5];
    const float* b_dyn   = (const float*)d_in[6];
    const float* W_gemb  = (const float*)d_in[7];
    const float* b_gemb  = (const float*)d_in[8];
    const float* Wih_g   = (const float*)d_in[9];
    const float* Whh_g   = (const float*)d_in[10];
    const float* bih_g   = (const float*)d_in[11];
    const float* bhh_g   = (const float*)d_in[12];
    const float* w_graph = (const float*)d_in[13];
    const float* Wih_c   = (const float*)d_in[14];
    const float* Whh_c   = (const float*)d_in[15];
    const float* bih_c   = (const float*)d_in[16];
    const float* bhh_c   = (const float*)d_in[17];
    const float* W_out   = (const float*)d_in[18];
    const float* b_out   = (const float*)d_in[19];

    float* out0 = (float*)d_out;                        // [S][N][5]
    float* chf = out0 + (size_t)Sx * Nx * OUTx;         // [N][64]
    float* ccf = chf + (size_t)Nx * 64;
    float* ghf = ccf + (size_t)Nx * 64;
    float* gcf = ghf + (size_t)Nx * 64;

    char* w = (char*)d_ws;
    float*  partials= (float*)w;                  w += (size_t)Sx * GRIDA * 64 * 4; // 4 MB
    float*  bias_all= (float*)w;                  w += Sx * 256 * 4;
    ushort* Wg      = (ushort*)w;                 w += 256 * KG * 2;
    ushort* Wc      = (ushort*)w;                 w += 256 * KC * 2;
    ushort* WoB     = (ushort*)w;                 w += 16 * 64 * 2;
    float*  Wfold2  = (float*)w;                  w += 64 * 256 * 4;
    float*  bsum_g  = (float*)w;                  w += 256 * 4;
    float*  bC0     = (float*)w;                  w += 256 * 4;

    k_prep<<<64, 256, 0, stream>>>(Wih_g, Whh_g, bih_g, bhh_g, w_graph,
                                   Wih_c, Whh_c, bih_c, bhh_c, W_out,
                                   Wg, Wc, WoB, Wfold2, bsum_g, bC0);

    k_graph_all<<<GRIDA, TPB, 0, stream>>>(input, graph_h0, graph_c0,
                                           W_gemb, b_gemb, Wg, bsum_g,
                                           partials, ghf, gcf);

    k_bias<<<Sx, 256, 0, stream>>>(partials, Wfold2, bC0, bias_all);

    k_cell_all<<<GRIDA, TPB, 0, stream>>>(input, graph_h0, graph_c0,
                                          cell_h0, cell_c0,
                                          W_gemb, b_gemb, Wg, bsum_g,
                                          W_dyn, b_dyn, Wc, bias_all,
                                          WoB, b_out,
                                          out0, chf, ccf);
}

// Round 10
// 1319.884 us; speedup vs baseline: 3.2389x; 3.2389x over previous
//
#include <hip/hip_runtime.h>

// GraphLSTM v6: round-9 recompute structure + weights in LDS + unroll control.
// A) k_graph_all: graph LSTM all 32 steps, gh/gc in regs; Wg staged in LDS.
// B) k_bias: partials -> bias_all[32][256].
// C) k_cell_all: recomputes graph recurrence (bit-identical), cell LSTM all
//    steps; Wg+Wc staged in LDS (154 KiB -> forces 1 block/CU -> unlocks the
//    >128-VGPR bucket, killing round-9's inner-loop spills); outputs via
//    2 MFMAs vs padded Wout^T.
// Per-wave weight reads now hit LDS (padded rows, 2-way conflicts = free)
// instead of 128 KB/wave/step from L2 (round-9's hidden floor).

#define Sx    32
#define Nx    65536
#define OUTx  5
#define KG    96              // graph gates K: [gemb(32) | gh(64)]
#define KC    160             // cell gates K:  [dyn(32) | gh(64) | ch(64)]
#define LWG   104             // lds row stride (ushorts) for Wg (96+8 pad)
#define LWC   168             // lds row stride (ushorts) for Wc (160+8 pad)
#define GRIDA 512             // blocks for A and C
#define TPB   512             // 8 waves x 16 nodes = 128 nodes/block

typedef __attribute__((ext_vector_type(4))) float f32x4;
typedef __attribute__((ext_vector_type(8))) short bf16x8;
typedef unsigned short ushort;
typedef unsigned int uint;

__device__ __forceinline__ float sigm(float x) {
    return __frcp_rn(1.f + __expf(-x));
}
__device__ __forceinline__ float tanh_fast(float x) {
    return fmaf(-2.f, __frcp_rn(1.f + __expf(2.f * x)), 1.f);
}
__device__ __forceinline__ ushort f2b(float x) {
    uint u = __float_as_uint(x);
    u += 0x7fffu + ((u >> 16) & 1u);   // RNE
    return (ushort)(u >> 16);
}

// ---------------- weight prep (once per launch, parallel) ----------------
__global__ __launch_bounds__(256) void k_prep(
    const float* __restrict__ Wih_g, const float* __restrict__ Whh_g,
    const float* __restrict__ bih_g, const float* __restrict__ bhh_g,
    const float* __restrict__ wgr,
    const float* __restrict__ Wih_c, const float* __restrict__ Whh_c,
    const float* __restrict__ bih_c, const float* __restrict__ bhh_c,
    const float* __restrict__ Wout,
    ushort* __restrict__ Wg, ushort* __restrict__ Wc,
    ushort* __restrict__ WoB,
    float* __restrict__ Wfold2,
    float* __restrict__ bsum_g, float* __restrict__ bC0)
{
    const int tid = blockIdx.x * 256 + threadIdx.x;
    const int nt = gridDim.x * 256;
    for (int idx = tid; idx < 256 * KG; idx += nt) {
        int col = idx / KG, k = idx % KG;
        float v = (k < 32) ? Wih_g[col * 32 + k] : Whh_g[col * 64 + (k - 32)];
        Wg[idx] = f2b(v);
    }
    for (int idx = tid; idx < 256 * KC; idx += nt) {
        int col = idx / KC, k = idx % KC;
        float v;
        if (k < 32) v = Wih_c[col * 64 + k];
        else if (k < 96) {
            int d = k - 32; float a = 0.f;
            for (int j = 0; j < 32; ++j)
                a = fmaf(wgr[d * 32 + j], Wih_c[col * 64 + 32 + j], a);
            v = -a;   // per-node part of loo is (-gh)
        } else v = Whh_c[col * 64 + (k - 96)];
        Wc[idx] = f2b(v);
    }
    for (int idx = tid; idx < 16 * 64; idx += nt) {
        int col = idx >> 6, k = idx & 63;
        WoB[idx] = (col < OUTx) ? f2b(Wout[col * 64 + k]) : (ushort)0;
    }
    for (int idx = tid; idx < 64 * 256; idx += nt) {
        int k = idx >> 8, col = idx & 255;
        float a = 0.f;
        for (int j = 0; j < 32; ++j)
            a = fmaf(wgr[k * 32 + j], Wih_c[col * 64 + 32 + j], a);
        Wfold2[idx] = a;
    }
    if (tid < 256) {
        bsum_g[tid] = bih_g[tid] + bhh_g[tid];
        bC0[tid]    = bih_c[tid] + bhh_c[tid];
    }
}

// ---------------- A: graph LSTM, all steps, partial sums only -------------
__global__ __launch_bounds__(TPB, 2) void k_graph_all(
    const float* __restrict__ input,               // [S][N][2]
    const float* __restrict__ gh0, const float* __restrict__ gc0,
    const float* __restrict__ Wge, const float* __restrict__ bge,
    const ushort* __restrict__ Wg, const float* __restrict__ bsum_g,
    float* __restrict__ partials,                  // [S][GRIDA][64]
    float* __restrict__ ghf, float* __restrict__ gcf)
{
    const int tid = threadIdx.x;
    const int wave = tid >> 6, lane = tid & 63;
    const int c = lane & 15, g4 = lane >> 4;
    const int nb = blockIdx.x * 128 + wave * 16;
    const int na = nb + c;

    __shared__ __align__(16) ushort lWg[256 * LWG];      // 53.2 KB
    __shared__ __align__(16) ushort t_lds[8][16][72];    // 18.4 KB
    __shared__ float wsum[2][8][64];

    // stage Wg -> LDS (padded rows), once
    {
        const uint* src = (const uint*)Wg;
        uint* dst = (uint*)lWg;
        for (int i = tid; i < 256 * (KG / 2); i += TPB)
            dst[(i / (KG / 2)) * (LWG / 2) + (i % (KG / 2))] = src[i];
    }
    __syncthreads();

    float gcr[4][4];
#pragma unroll
    for (int q = 0; q < 4; ++q)
#pragma unroll
        for (int r = 0; r < 4; ++r)
            gcr[q][r] = gc0[(nb + 4 * g4 + r) * 64 + 16 * q + c];
    bf16x8 agh0, agh1;
#pragma unroll
    for (int j = 0; j < 8; ++j) {
        agh0[j] = (short)f2b(gh0[na * 64 + g4 * 8 + j]);
        agh1[j] = (short)f2b(gh0[na * 64 + 32 + g4 * 8 + j]);
    }

#pragma unroll 1
    for (int t = 0; t < Sx; ++t) {
        const float* frame = input + (size_t)t * Nx * 2;
        const float f0 = frame[2 * na], f1 = frame[2 * na + 1];
        const int lastt = (t == Sx - 1);
        bf16x8 a0;
#pragma unroll
        for (int j = 0; j < 8; ++j) {
            const int k = g4 * 8 + j;
            float v = fmaf(f1, Wge[2 * k + 1], fmaf(f0, Wge[2 * k], bge[k]));
            a0[j] = (short)f2b(fmaxf(v, 0.f));
        }
        float hsq[4];
#pragma unroll 1
        for (int q = 0; q < 4; ++q) {
            f32x4 acc[4];
#pragma unroll
            for (int g = 0; g < 4; ++g) {
                acc[g] = (f32x4){0.f, 0.f, 0.f, 0.f};
                const ushort* wp = lWg + (16 * (4 * g + q) + c) * LWG + g4 * 8;
                bf16x8 b0 = *(const bf16x8*)(wp);
                bf16x8 b1 = *(const bf16x8*)(wp + 32);
                bf16x8 b2 = *(const bf16x8*)(wp + 64);
                acc[g] = __builtin_amdgcn_mfma_f32_16x16x32_bf16(a0,   b0, acc[g], 0, 0, 0);
                acc[g] = __builtin_amdgcn_mfma_f32_16x16x32_bf16(agh0, b1, acc[g], 0, 0, 0);
                acc[g] = __builtin_amdgcn_mfma_f32_16x16x32_bf16(agh1, b2, acc[g], 0, 0, 0);
            }
            const int d = 16 * q + c;
            const float bi = bsum_g[d], bf = bsum_g[64 + d],
                        bg = bsum_g[128 + d], bo = bsum_g[192 + d];
            float s_r = 0.f;
#pragma unroll
            for (int r = 0; r < 4; ++r) {
                const float ai = acc[0][r] + bi, af = acc[1][r] + bf,
                            ag = acc[2][r] + bg, ao = acc[3][r] + bo;
                const float c2 = fmaf(sigm(af), gcr[q][r], sigm(ai) * tanh_fast(ag));
                gcr[q][r] = c2;
                const float h2 = sigm(ao) * tanh_fast(c2);
                t_lds[wave][4 * g4 + r][16 * q + c] = f2b(h2);
                if (lastt) {
                    const int n = nb + 4 * g4 + r;
                    ghf[n * 64 + d] = h2;
                    gcf[n * 64 + d] = c2;
                }
                s_r += h2;
            }
            hsq[q] = s_r;
        }
#pragma unroll
        for (int q = 0; q < 4; ++q) {
            float v = hsq[q];
            v += __shfl_xor(v, 16);
            v += __shfl_xor(v, 32);
            hsq[q] = v;
        }
        if (g4 == 0) {
#pragma unroll
            for (int q = 0; q < 4; ++q) wsum[t & 1][wave][16 * q + c] = hsq[q];
        }
        __syncthreads();
        agh0 = *(const bf16x8*)(&t_lds[wave][c][g4 * 8]);        // gh(t)
        agh1 = *(const bf16x8*)(&t_lds[wave][c][32 + g4 * 8]);
        if (tid < 64) {
            float a = 0.f;
#pragma unroll
            for (int w8 = 0; w8 < 8; ++w8) a += wsum[t & 1][w8][tid];
            partials[((size_t)t * GRIDA + blockIdx.x) * 64 + tid] = a;
        }
    }
}

// ---------------- B: per-step bias from partials ---------------------------
__global__ __launch_bounds__(256) void k_bias(
    const float* __restrict__ partials,   // [S][GRIDA][64]
    const float* __restrict__ Wfold2, const float* __restrict__ bC0,
    float* __restrict__ bias_all)         // [S][256]
{
    const int t = blockIdx.x, tid = threadIdx.x;
    __shared__ float red[4][64];
    __shared__ float S[64];
    const int d = tid & 63, j = tid >> 6;
    float a = 0.f;
    for (int b = j; b < GRIDA; b += 4)
        a += partials[((size_t)t * GRIDA + b) * 64 + d];
    red[j][d] = a;
    __syncthreads();
    if (tid < 64) S[tid] = red[0][tid] + red[1][tid] + red[2][tid] + red[3][tid];
    __syncthreads();
    float bv = bC0[tid];
#pragma unroll
    for (int k = 0; k < 64; ++k) bv = fmaf(S[k], Wfold2[k * 256 + tid], bv);
    bias_all[t * 256 + tid] = bv;
}

// ---------------- C: graph recompute + cell LSTM, all steps ----------------
__global__ __launch_bounds__(TPB, 2) void k_cell_all(
    const float* __restrict__ input,               // [S][N][2]
    const float* __restrict__ gh0, const float* __restrict__ gc0,
    const float* __restrict__ ch0, const float* __restrict__ cc0,
    const float* __restrict__ Wge, const float* __restrict__ bge,
    const ushort* __restrict__ Wg, const float* __restrict__ bsum_g,
    const float* __restrict__ Wdy, const float* __restrict__ bdy,
    const ushort* __restrict__ Wc, const float* __restrict__ bias_all,
    const ushort* __restrict__ WoB, const float* __restrict__ bo5,
    float* __restrict__ out0,                      // [S][N][5]
    float* __restrict__ chf, float* __restrict__ ccf)
{
    const int tid = threadIdx.x;
    const int wave = tid >> 6, lane = tid & 63;
    const int c = lane & 15, g4 = lane >> 4;
    const int nb = blockIdx.x * 128 + wave * 16;
    const int na = nb + c;

    // 53.2 + 86.0 + 18.4 = 157.6 KB static LDS -> forces 1 block/CU,
    // which unlocks the >128-VGPR allocation bucket (no spills).
    __shared__ __align__(16) ushort lWg[256 * LWG];
    __shared__ __align__(16) ushort lWc[256 * LWC];
    __shared__ __align__(16) ushort t_lds[8][16][72];

    {
        const uint* src = (const uint*)Wg;
        uint* dst = (uint*)lWg;
        for (int i = tid; i < 256 * (KG / 2); i += TPB)
            dst[(i / (KG / 2)) * (LWG / 2) + (i % (KG / 2))] = src[i];
        const uint* src2 = (const uint*)Wc;
        uint* dst2 = (uint*)lWc;
        for (int i = tid; i < 256 * (KC / 2); i += TPB)
            dst2[(i / (KC / 2)) * (LWC / 2) + (i % (KC / 2))] = src2[i];
    }
    __syncthreads();

    float gcr[4][4], ccr[4][4];
#pragma unroll
    for (int q = 0; q < 4; ++q)
#pragma unroll
        for (int r = 0; r < 4; ++r) {
            const int n = nb + 4 * g4 + r, d = 16 * q + c;
            gcr[q][r] = gc0[n * 64 + d];
            ccr[q][r] = cc0[n * 64 + d];
        }
    bf16x8 agh0, agh1, ach0, ach1;
#pragma unroll
    for (int j = 0; j < 8; ++j) {
        agh0[j] = (short)f2b(gh0[na * 64 + g4 * 8 + j]);
        agh1[j] = (short)f2b(gh0[na * 64 + 32 + g4 * 8 + j]);
        ach0[j] = (short)f2b(ch0[na * 64 + g4 * 8 + j]);
        ach1[j] = (short)f2b(ch0[na * 64 + 32 + g4 * 8 + j]);
    }
    bf16x8 woB0 = *(const bf16x8*)(WoB + c * 64 + g4 * 8);
    bf16x8 woB1 = *(const bf16x8*)(WoB + c * 64 + 32 + g4 * 8);
    const float bo_c = (c < OUTx) ? bo5[c] : 0.f;

#pragma unroll 1
    for (int t = 0; t < Sx; ++t) {
        const float* frame = input + (size_t)t * Nx * 2;
        const float f0 = frame[2 * na], f1 = frame[2 * na + 1];
        const int lastt = (t == Sx - 1);

        // ===== graph recompute (bit-identical to k_graph_all) =====
        bf16x8 a0;
#pragma unroll
        for (int j = 0; j < 8; ++j) {
            const int k = g4 * 8 + j;
            float v = fmaf(f1, Wge[2 * k + 1], fmaf(f0, Wge[2 * k], bge[k]));
            a0[j] = (short)f2b(fmaxf(v, 0.f));
        }
#pragma unroll 1
        for (int q = 0; q < 4; ++q) {
            f32x4 acc[4];
#pragma unroll
            for (int g = 0; g < 4; ++g) {
                acc[g] = (f32x4){0.f, 0.f, 0.f, 0.f};
                const ushort* wp = lWg + (16 * (4 * g + q) + c) * LWG + g4 * 8;
                bf16x8 b0 = *(const bf16x8*)(wp);
                bf16x8 b1 = *(const bf16x8*)(wp + 32);
                bf16x8 b2 = *(const bf16x8*)(wp + 64);
                acc[g] = __builtin_amdgcn_mfma_f32_16x16x32_bf16(a0,   b0, acc[g], 0, 0, 0);
                acc[g] = __builtin_amdgcn_mfma_f32_16x16x32_bf16(agh0, b1, acc[g], 0, 0, 0);
                acc[g] = __builtin_amdgcn_mfma_f32_16x16x32_bf16(agh1, b2, acc[g], 0, 0, 0);
            }
            const int d = 16 * q + c;
            const float bi = bsum_g[d], bf = bsum_g[64 + d],
                        bg = bsum_g[128 + d], bo = bsum_g[192 + d];
#pragma unroll
            for (int r = 0; r < 4; ++r) {
                const float ai = acc[0][r] + bi, af = acc[1][r] + bf,
                            ag = acc[2][r] + bg, ao = acc[3][r] + bo;
                const float c2 = fmaf(sigm(af), gcr[q][r], sigm(ai) * tanh_fast(ag));
                gcr[q][r] = c2;
                const float h2 = sigm(ao) * tanh_fast(c2);
                t_lds[wave][4 * g4 + r][16 * q + c] = f2b(h2);
            }
        }
        agh0 = *(const bf16x8*)(&t_lds[wave][c][g4 * 8]);        // gh(t)
        agh1 = *(const bf16x8*)(&t_lds[wave][c][32 + g4 * 8]);

        // ===== cell phase (agh=gh(t), ach=ch(t-1)) =====
        bf16x8 a0c;
#pragma unroll
        for (int j = 0; j < 8; ++j) {
            const int k = g4 * 8 + j;
            float v = fmaf(f1, Wdy[2 * k + 1], fmaf(f0, Wdy[2 * k], bdy[k]));
            a0c[j] = (short)f2b(fmaxf(v, 0.f));
        }
#pragma unroll 1
        for (int q = 0; q < 4; ++q) {
            f32x4 acc[4];
#pragma unroll
            for (int g = 0; g < 4; ++g) {
                acc[g] = (f32x4){0.f, 0.f, 0.f, 0.f};
                const ushort* wp = lWc + (16 * (4 * g + q) + c) * LWC + g4 * 8;
                bf16x8 b0 = *(const bf16x8*)(wp);
                bf16x8 b1 = *(const bf16x8*)(wp + 32);
                bf16x8 b2 = *(const bf16x8*)(wp + 64);
                bf16x8 b3 = *(const bf16x8*)(wp + 96);
                bf16x8 b4 = *(const bf16x8*)(wp + 128);
                acc[g] = __builtin_amdgcn_mfma_f32_16x16x32_bf16(a0c,  b0, acc[g], 0, 0, 0);
                acc[g] = __builtin_amdgcn_mfma_f32_16x16x32_bf16(agh0, b1, acc[g], 0, 0, 0);
                acc[g] = __builtin_amdgcn_mfma_f32_16x16x32_bf16(agh1, b2, acc[g], 0, 0, 0);
                acc[g] = __builtin_amdgcn_mfma_f32_16x16x32_bf16(ach0, b3, acc[g], 0, 0, 0);
                acc[g] = __builtin_amdgcn_mfma_f32_16x16x32_bf16(ach1, b4, acc[g], 0, 0, 0);
            }
            const int d = 16 * q + c;
            const float bi = bias_all[t * 256 + d],
                        bf = bias_all[t * 256 + 64 + d],
                        bg = bias_all[t * 256 + 128 + d],
                        bov = bias_all[t * 256 + 192 + d];
#pragma unroll
            for (int r = 0; r < 4; ++r) {
                const float ai = acc[0][r] + bi, af = acc[1][r] + bf,
                            ag = acc[2][r] + bg, ao = acc[3][r] + bov;
                const float c2 = fmaf(sigm(af), ccr[q][r], sigm(ai) * tanh_fast(ag));
                ccr[q][r] = c2;
                const float h2 = sigm(ao) * tanh_fast(c2);
                t_lds[wave][4 * g4 + r][16 * q + c] = f2b(h2);
                if (lastt) {
                    const int n = nb + 4 * g4 + r;
                    chf[n * 64 + d] = h2;
                    ccf[n * 64 + d] = c2;
                }
            }
        }
        ach0 = *(const bf16x8*)(&t_lds[wave][c][g4 * 8]);        // ch(t)
        ach1 = *(const bf16x8*)(&t_lds[wave][c][32 + g4 * 8]);

        // ===== outputs: out = ch(t) @ Wout^T via 2 MFMAs =====
        {
            f32x4 oa = (f32x4){0.f, 0.f, 0.f, 0.f};
            oa = __builtin_amdgcn_mfma_f32_16x16x32_bf16(ach0, woB0, oa, 0, 0, 0);
            oa = __builtin_amdgcn_mfma_f32_16x16x32_bf16(ach1, woB1, oa, 0, 0, 0);
            if (c < OUTx) {
                float* outp = out0 + (size_t)t * Nx * OUTx;
#pragma unroll
                for (int r = 0; r < 4; ++r)
                    outp[(nb + 4 * g4 + r) * OUTx + c] = oa[r] + bo_c;
            }
        }
    }
}

extern "C" void kernel_launch(void* const* d_in, const int* in_sizes, int n_in,
                              void* d_out, int out_size, void* d_ws, size_t ws_size,
                              hipStream_t stream) {
    const float* input   = (const float*)d_in[0];   // [S][N][2]
    const float* cell_h0 = (const float*)d_in[1];
    const float* cell_c0 = (const float*)d_in[2];
    const float* graph_h0= (const float*)d_in[3];
    const float* graph_c0= (const float*)d_in[4];
    const float* W_dyn   = (const float*)d_in[5];
    const float* b_dyn   = (const float*)d_in[6];
    const float* W_gemb  = (const float*)d_in[7];
    const float* b_gemb  = (const float*)d_in[8];
    const float* Wih_g   = (const float*)d_in[9];
    const float* Whh_g   = (const float*)d_in[10];
    const float* bih_g   = (const float*)d_in[11];
    const float* bhh_g   = (const float*)d_in[12];
    const float* w_graph = (const float*)d_in[13];
    const float* Wih_c   = (const float*)d_in[14];
    const float* Whh_c   = (const float*)d_in[15];
    const float* bih_c   = (const float*)d_in[16];
    const float* bhh_c   = (const float*)d_in[17];
    const float* W_out   = (const float*)d_in[18];
    const float* b_out   = (const float*)d_in[19];

    float* out0 = (float*)d_out;                        // [S][N][5]
    float* chf = out0 + (size_t)Sx * Nx * OUTx;         // [N][64]
    float* ccf = chf + (size_t)Nx * 64;
    float* ghf = ccf + (size_t)Nx * 64;
    float* gcf = ghf + (size_t)Nx * 64;

    char* w = (char*)d_ws;
    float*  partials= (float*)w;                  w += (size_t)Sx * GRIDA * 64 * 4; // 4 MB
    float*  bias_all= (float*)w;                  w += Sx * 256 * 4;
    ushort* Wg      = (ushort*)w;                 w += 256 * KG * 2;
    ushort* Wc      = (ushort*)w;                 w += 256 * KC * 2;
    ushort* WoB     = (ushort*)w;                 w += 16 * 64 * 2;
    float*  Wfold2  = (float*)w;                  w += 64 * 256 * 4;
    float*  bsum_g  = (float*)w;                  w += 256 * 4;
    float*  bC0     = (float*)w;                  w += 256 * 4;

    k_prep<<<64, 256, 0, stream>>>(Wih_g, Whh_g, bih_g, bhh_g, w_graph,
                                   Wih_c, Whh_c, bih_c, bhh_c, W_out,
                                   Wg, Wc, WoB, Wfold2, bsum_g, bC0);

    k_graph_all<<<GRIDA, TPB, 0, stream>>>(input, graph_h0, graph_c0,
                                           W_gemb, b_gemb, Wg, bsum_g,
                                           partials, ghf, gcf);

    k_bias<<<Sx, 256, 0, stream>>>(partials, Wfold2, bC0, bias_all);

    k_cell_all<<<GRIDA, TPB, 0, stream>>>(input, graph_h0, graph_c0,
                                          cell_h0, cell_c0,
                                          W_gemb, b_gemb, Wg, bsum_g,
                                          W_dyn, b_dyn, Wc, bias_all,
                                          WoB, b_out,
                                          out0, chf, ccf);
}

// Round 11
// 838.850 us; speedup vs baseline: 5.0963x; 1.5734x over previous
//
#include <hip/hip_runtime.h>

// GraphLSTM v7 = round-10 structure + fast transcendentals.
// Round-10 counters: k_cell_all VALUBusy 79.9%, MfmaUtil 12.3%, FETCH 42 MB
// (spills eliminated by LDS-forced 1 block/CU). VALU is the bound; the
// biggest consumer is 160 __frcp_rn/thread/step in sigmoid/tanh.
// Change: __frcp_rn -> __builtin_amdgcn_rcpf (single v_rcp_f32, ~1ulp --
// invisible vs bf16 rounding). Everything else frozen.

#define Sx    32
#define Nx    65536
#define OUTx  5
#define KG    96              // graph gates K: [gemb(32) | gh(64)]
#define KC    160             // cell gates K:  [dyn(32) | gh(64) | ch(64)]
#define LWG   104             // lds row stride (ushorts) for Wg (96+8 pad)
#define LWC   168             // lds row stride (ushorts) for Wc (160+8 pad)
#define GRIDA 512             // blocks for A and C
#define TPB   512             // 8 waves x 16 nodes = 128 nodes/block

typedef __attribute__((ext_vector_type(4))) float f32x4;
typedef __attribute__((ext_vector_type(8))) short bf16x8;
typedef unsigned short ushort;
typedef unsigned int uint;

__device__ __forceinline__ float sigm(float x) {
    return __builtin_amdgcn_rcpf(1.f + __expf(-x));
}
__device__ __forceinline__ float tanh_fast(float x) {
    return fmaf(-2.f, __builtin_amdgcn_rcpf(1.f + __expf(2.f * x)), 1.f);
}
__device__ __forceinline__ ushort f2b(float x) {
    uint u = __float_as_uint(x);
    u += 0x7fffu + ((u >> 16) & 1u);   // RNE
    return (ushort)(u >> 16);
}

// ---------------- weight prep (once per launch, parallel) ----------------
__global__ __launch_bounds__(256) void k_prep(
    const float* __restrict__ Wih_g, const float* __restrict__ Whh_g,
    const float* __restrict__ bih_g, const float* __restrict__ bhh_g,
    const float* __restrict__ wgr,
    const float* __restrict__ Wih_c, const float* __restrict__ Whh_c,
    const float* __restrict__ bih_c, const float* __restrict__ bhh_c,
    const float* __restrict__ Wout,
    ushort* __restrict__ Wg, ushort* __restrict__ Wc,
    ushort* __restrict__ WoB,
    float* __restrict__ Wfold2,
    float* __restrict__ bsum_g, float* __restrict__ bC0)
{
    const int tid = blockIdx.x * 256 + threadIdx.x;
    const int nt = gridDim.x * 256;
    for (int idx = tid; idx < 256 * KG; idx += nt) {
        int col = idx / KG, k = idx % KG;
        float v = (k < 32) ? Wih_g[col * 32 + k] : Whh_g[col * 64 + (k - 32)];
        Wg[idx] = f2b(v);
    }
    for (int idx = tid; idx < 256 * KC; idx += nt) {
        int col = idx / KC, k = idx % KC;
        float v;
        if (k < 32) v = Wih_c[col * 64 + k];
        else if (k < 96) {
            int d = k - 32; float a = 0.f;
            for (int j = 0; j < 32; ++j)
                a = fmaf(wgr[d * 32 + j], Wih_c[col * 64 + 32 + j], a);
            v = -a;   // per-node part of loo is (-gh)
        } else v = Whh_c[col * 64 + (k - 96)];
        Wc[idx] = f2b(v);
    }
    for (int idx = tid; idx < 16 * 64; idx += nt) {
        int col = idx >> 6, k = idx & 63;
        WoB[idx] = (col < OUTx) ? f2b(Wout[col * 64 + k]) : (ushort)0;
    }
    for (int idx = tid; idx < 64 * 256; idx += nt) {
        int k = idx >> 8, col = idx & 255;
        float a = 0.f;
        for (int j = 0; j < 32; ++j)
            a = fmaf(wgr[k * 32 + j], Wih_c[col * 64 + 32 + j], a);
        Wfold2[idx] = a;
    }
    if (tid < 256) {
        bsum_g[tid] = bih_g[tid] + bhh_g[tid];
        bC0[tid]    = bih_c[tid] + bhh_c[tid];
    }
}

// ---------------- A: graph LSTM, all steps, partial sums only -------------
__global__ __launch_bounds__(TPB, 2) void k_graph_all(
    const float* __restrict__ input,               // [S][N][2]
    const float* __restrict__ gh0, const float* __restrict__ gc0,
    const float* __restrict__ Wge, const float* __restrict__ bge,
    const ushort* __restrict__ Wg, const float* __restrict__ bsum_g,
    float* __restrict__ partials,                  // [S][GRIDA][64]
    float* __restrict__ ghf, float* __restrict__ gcf)
{
    const int tid = threadIdx.x;
    const int wave = tid >> 6, lane = tid & 63;
    const int c = lane & 15, g4 = lane >> 4;
    const int nb = blockIdx.x * 128 + wave * 16;
    const int na = nb + c;

    __shared__ __align__(16) ushort lWg[256 * LWG];      // 53.2 KB
    __shared__ __align__(16) ushort t_lds[8][16][72];    // 18.4 KB
    __shared__ float wsum[2][8][64];

    {
        const uint* src = (const uint*)Wg;
        uint* dst = (uint*)lWg;
        for (int i = tid; i < 256 * (KG / 2); i += TPB)
            dst[(i / (KG / 2)) * (LWG / 2) + (i % (KG / 2))] = src[i];
    }
    __syncthreads();

    float gcr[4][4];
#pragma unroll
    for (int q = 0; q < 4; ++q)
#pragma unroll
        for (int r = 0; r < 4; ++r)
            gcr[q][r] = gc0[(nb + 4 * g4 + r) * 64 + 16 * q + c];
    bf16x8 agh0, agh1;
#pragma unroll
    for (int j = 0; j < 8; ++j) {
        agh0[j] = (short)f2b(gh0[na * 64 + g4 * 8 + j]);
        agh1[j] = (short)f2b(gh0[na * 64 + 32 + g4 * 8 + j]);
    }

#pragma unroll 1
    for (int t = 0; t < Sx; ++t) {
        const float* frame = input + (size_t)t * Nx * 2;
        const float f0 = frame[2 * na], f1 = frame[2 * na + 1];
        const int lastt = (t == Sx - 1);
        bf16x8 a0;
#pragma unroll
        for (int j = 0; j < 8; ++j) {
            const int k = g4 * 8 + j;
            float v = fmaf(f1, Wge[2 * k + 1], fmaf(f0, Wge[2 * k], bge[k]));
            a0[j] = (short)f2b(fmaxf(v, 0.f));
        }
        float hsq[4];
#pragma unroll 1
        for (int q = 0; q < 4; ++q) {
            f32x4 acc[4];
#pragma unroll
            for (int g = 0; g < 4; ++g) {
                acc[g] = (f32x4){0.f, 0.f, 0.f, 0.f};
                const ushort* wp = lWg + (16 * (4 * g + q) + c) * LWG + g4 * 8;
                bf16x8 b0 = *(const bf16x8*)(wp);
                bf16x8 b1 = *(const bf16x8*)(wp + 32);
                bf16x8 b2 = *(const bf16x8*)(wp + 64);
                acc[g] = __builtin_amdgcn_mfma_f32_16x16x32_bf16(a0,   b0, acc[g], 0, 0, 0);
                acc[g] = __builtin_amdgcn_mfma_f32_16x16x32_bf16(agh0, b1, acc[g], 0, 0, 0);
                acc[g] = __builtin_amdgcn_mfma_f32_16x16x32_bf16(agh1, b2, acc[g], 0, 0, 0);
            }
            const int d = 16 * q + c;
            const float bi = bsum_g[d], bf = bsum_g[64 + d],
                        bg = bsum_g[128 + d], bo = bsum_g[192 + d];
            float s_r = 0.f;
#pragma unroll
            for (int r = 0; r < 4; ++r) {
                const float ai = acc[0][r] + bi, af = acc[1][r] + bf,
                            ag = acc[2][r] + bg, ao = acc[3][r] + bo;
                const float c2 = fmaf(sigm(af), gcr[q][r], sigm(ai) * tanh_fast(ag));
                gcr[q][r] = c2;
                const float h2 = sigm(ao) * tanh_fast(c2);
                t_lds[wave][4 * g4 + r][16 * q + c] = f2b(h2);
                if (lastt) {
                    const int n = nb + 4 * g4 + r;
                    ghf[n * 64 + d] = h2;
                    gcf[n * 64 + d] = c2;
                }
                s_r += h2;
            }
            hsq[q] = s_r;
        }
#pragma unroll
        for (int q = 0; q < 4; ++q) {
            float v = hsq[q];
            v += __shfl_xor(v, 16);
            v += __shfl_xor(v, 32);
            hsq[q] = v;
        }
        if (g4 == 0) {
#pragma unroll
            for (int q = 0; q < 4; ++q) wsum[t & 1][wave][16 * q + c] = hsq[q];
        }
        __syncthreads();
        agh0 = *(const bf16x8*)(&t_lds[wave][c][g4 * 8]);        // gh(t)
        agh1 = *(const bf16x8*)(&t_lds[wave][c][32 + g4 * 8]);
        if (tid < 64) {
            float a = 0.f;
#pragma unroll
            for (int w8 = 0; w8 < 8; ++w8) a += wsum[t & 1][w8][tid];
            partials[((size_t)t * GRIDA + blockIdx.x) * 64 + tid] = a;
        }
    }
}

// ---------------- B: per-step bias from partials ---------------------------
__global__ __launch_bounds__(256) void k_bias(
    const float* __restrict__ partials,   // [S][GRIDA][64]
    const float* __restrict__ Wfold2, const float* __restrict__ bC0,
    float* __restrict__ bias_all)         // [S][256]
{
    const int t = blockIdx.x, tid = threadIdx.x;
    __shared__ float red[4][64];
    __shared__ float S[64];
    const int d = tid & 63, j = tid >> 6;
    float a = 0.f;
    for (int b = j; b < GRIDA; b += 4)
        a += partials[((size_t)t * GRIDA + b) * 64 + d];
    red[j][d] = a;
    __syncthreads();
    if (tid < 64) S[tid] = red[0][tid] + red[1][tid] + red[2][tid] + red[3][tid];
    __syncthreads();
    float bv = bC0[tid];
#pragma unroll
    for (int k = 0; k < 64; ++k) bv = fmaf(S[k], Wfold2[k * 256 + tid], bv);
    bias_all[t * 256 + tid] = bv;
}

// ---------------- C: graph recompute + cell LSTM, all steps ----------------
__global__ __launch_bounds__(TPB, 2) void k_cell_all(
    const float* __restrict__ input,               // [S][N][2]
    const float* __restrict__ gh0, const float* __restrict__ gc0,
    const float* __restrict__ ch0, const float* __restrict__ cc0,
    const float* __restrict__ Wge, const float* __restrict__ bge,
    const ushort* __restrict__ Wg, const float* __restrict__ bsum_g,
    const float* __restrict__ Wdy, const float* __restrict__ bdy,
    const ushort* __restrict__ Wc, const float* __restrict__ bias_all,
    const ushort* __restrict__ WoB, const float* __restrict__ bo5,
    float* __restrict__ out0,                      // [S][N][5]
    float* __restrict__ chf, float* __restrict__ ccf)
{
    const int tid = threadIdx.x;
    const int wave = tid >> 6, lane = tid & 63;
    const int c = lane & 15, g4 = lane >> 4;
    const int nb = blockIdx.x * 128 + wave * 16;
    const int na = nb + c;

    __shared__ __align__(16) ushort lWg[256 * LWG];
    __shared__ __align__(16) ushort lWc[256 * LWC];
    __shared__ __align__(16) ushort t_lds[8][16][72];

    {
        const uint* src = (const uint*)Wg;
        uint* dst = (uint*)lWg;
        for (int i = tid; i < 256 * (KG / 2); i += TPB)
            dst[(i / (KG / 2)) * (LWG / 2) + (i % (KG / 2))] = src[i];
        const uint* src2 = (const uint*)Wc;
        uint* dst2 = (uint*)lWc;
        for (int i = tid; i < 256 * (KC / 2); i += TPB)
            dst2[(i / (KC / 2)) * (LWC / 2) + (i % (KC / 2))] = src2[i];
    }
    __syncthreads();

    float gcr[4][4], ccr[4][4];
#pragma unroll
    for (int q = 0; q < 4; ++q)
#pragma unroll
        for (int r = 0; r < 4; ++r) {
            const int n = nb + 4 * g4 + r, d = 16 * q + c;
            gcr[q][r] = gc0[n * 64 + d];
            ccr[q][r] = cc0[n * 64 + d];
        }
    bf16x8 agh0, agh1, ach0, ach1;
#pragma unroll
    for (int j = 0; j < 8; ++j) {
        agh0[j] = (short)f2b(gh0[na * 64 + g4 * 8 + j]);
        agh1[j] = (short)f2b(gh0[na * 64 + 32 + g4 * 8 + j]);
        ach0[j] = (short)f2b(ch0[na * 64 + g4 * 8 + j]);
        ach1[j] = (short)f2b(ch0[na * 64 + 32 + g4 * 8 + j]);
    }
    bf16x8 woB0 = *(const bf16x8*)(WoB + c * 64 + g4 * 8);
    bf16x8 woB1 = *(const bf16x8*)(WoB + c * 64 + 32 + g4 * 8);
    const float bo_c = (c < OUTx) ? bo5[c] : 0.f;

#pragma unroll 1
    for (int t = 0; t < Sx; ++t) {
        const float* frame = input + (size_t)t * Nx * 2;
        const float f0 = frame[2 * na], f1 = frame[2 * na + 1];
        const int lastt = (t == Sx - 1);

        // ===== graph recompute (bit-identical to k_graph_all) =====
        bf16x8 a0;
#pragma unroll
        for (int j = 0; j < 8; ++j) {
            const int k = g4 * 8 + j;
            float v = fmaf(f1, Wge[2 * k + 1], fmaf(f0, Wge[2 * k], bge[k]));
            a0[j] = (short)f2b(fmaxf(v, 0.f));
        }
#pragma unroll 1
        for (int q = 0; q < 4; ++q) {
            f32x4 acc[4];
#pragma unroll
            for (int g = 0; g < 4; ++g) {
                acc[g] = (f32x4){0.f, 0.f, 0.f, 0.f};
                const ushort* wp = lWg + (16 * (4 * g + q) + c) * LWG + g4 * 8;
                bf16x8 b0 = *(const bf16x8*)(wp);
                bf16x8 b1 = *(const bf16x8*)(wp + 32);
                bf16x8 b2 = *(const bf16x8*)(wp + 64);
                acc[g] = __builtin_amdgcn_mfma_f32_16x16x32_bf16(a0,   b0, acc[g], 0, 0, 0);
                acc[g] = __builtin_amdgcn_mfma_f32_16x16x32_bf16(agh0, b1, acc[g], 0, 0, 0);
                acc[g] = __builtin_amdgcn_mfma_f32_16x16x32_bf16(agh1, b2, acc[g], 0, 0, 0);
            }
            const int d = 16 * q + c;
            const float bi = bsum_g[d], bf = bsum_g[64 + d],
                        bg = bsum_g[128 + d], bo = bsum_g[192 + d];
#pragma unroll
            for (int r = 0; r < 4; ++r) {
                const float ai = acc[0][r] + bi, af = acc[1][r] + bf,
                            ag = acc[2][r] + bg, ao = acc[3][r] + bo;
                const float c2 = fmaf(sigm(af), gcr[q][r], sigm(ai) * tanh_fast(ag));
                gcr[q][r] = c2;
                const float h2 = sigm(ao) * tanh_fast(c2);
                t_lds[wave][4 * g4 + r][16 * q + c] = f2b(h2);
            }
        }
        agh0 = *(const bf16x8*)(&t_lds[wave][c][g4 * 8]);        // gh(t)
        agh1 = *(const bf16x8*)(&t_lds[wave][c][32 + g4 * 8]);

        // ===== cell phase (agh=gh(t), ach=ch(t-1)) =====
        bf16x8 a0c;
#pragma unroll
        for (int j = 0; j < 8; ++j) {
            const int k = g4 * 8 + j;
            float v = fmaf(f1, Wdy[2 * k + 1], fmaf(f0, Wdy[2 * k], bdy[k]));
            a0c[j] = (short)f2b(fmaxf(v, 0.f));
        }
#pragma unroll 1
        for (int q = 0; q < 4; ++q) {
            f32x4 acc[4];
#pragma unroll
            for (int g = 0; g < 4; ++g) {
                acc[g] = (f32x4){0.f, 0.f, 0.f, 0.f};
                const ushort* wp = lWc + (16 * (4 * g + q) + c) * LWC + g4 * 8;
                bf16x8 b0 = *(const bf16x8*)(wp);
                bf16x8 b1 = *(const bf16x8*)(wp + 32);
                bf16x8 b2 = *(const bf16x8*)(wp + 64);
                bf16x8 b3 = *(const bf16x8*)(wp + 96);
                bf16x8 b4 = *(const bf16x8*)(wp + 128);
                acc[g] = __builtin_amdgcn_mfma_f32_16x16x32_bf16(a0c,  b0, acc[g], 0, 0, 0);
                acc[g] = __builtin_amdgcn_mfma_f32_16x16x32_bf16(agh0, b1, acc[g], 0, 0, 0);
                acc[g] = __builtin_amdgcn_mfma_f32_16x16x32_bf16(agh1, b2, acc[g], 0, 0, 0);
                acc[g] = __builtin_amdgcn_mfma_f32_16x16x32_bf16(ach0, b3, acc[g], 0, 0, 0);
                acc[g] = __builtin_amdgcn_mfma_f32_16x16x32_bf16(ach1, b4, acc[g], 0, 0, 0);
            }
            const int d = 16 * q + c;
            const float bi = bias_all[t * 256 + d],
                        bf = bias_all[t * 256 + 64 + d],
                        bg = bias_all[t * 256 + 128 + d],
                        bov = bias_all[t * 256 + 192 + d];
#pragma unroll
            for (int r = 0; r < 4; ++r) {
                const float ai = acc[0][r] + bi, af = acc[1][r] + bf,
                            ag = acc[2][r] + bg, ao = acc[3][r] + bov;
                const float c2 = fmaf(sigm(af), ccr[q][r], sigm(ai) * tanh_fast(ag));
                ccr[q][r] = c2;
                const float h2 = sigm(ao) * tanh_fast(c2);
                t_lds[wave][4 * g4 + r][16 * q + c] = f2b(h2);
                if (lastt) {
                    const int n = nb + 4 * g4 + r;
                    chf[n * 64 + d] = h2;
                    ccf[n * 64 + d] = c2;
                }
            }
        }
        ach0 = *(const bf16x8*)(&t_lds[wave][c][g4 * 8]);        // ch(t)
        ach1 = *(const bf16x8*)(&t_lds[wave][c][32 + g4 * 8]);

        // ===== outputs: out = ch(t) @ Wout^T via 2 MFMAs =====
        {
            f32x4 oa = (f32x4){0.f, 0.f, 0.f, 0.f};
            oa = __builtin_amdgcn_mfma_f32_16x16x32_bf16(ach0, woB0, oa, 0, 0, 0);
            oa = __builtin_amdgcn_mfma_f32_16x16x32_bf16(ach1, woB1, oa, 0, 0, 0);
            if (c < OUTx) {
                float* outp = out0 + (size_t)t * Nx * OUTx;
#pragma unroll
                for (int r = 0; r < 4; ++r)
                    outp[(nb + 4 * g4 + r) * OUTx + c] = oa[r] + bo_c;
            }
        }
    }
}

extern "C" void kernel_launch(void* const* d_in, const int* in_sizes, int n_in,
                              void* d_out, int out_size, void* d_ws, size_t ws_size,
                              hipStream_t stream) {
    const float* input   = (const float*)d_in[0];   // [S][N][2]
    const float* cell_h0 = (const float*)d_in[1];
    const float* cell_c0 = (const float*)d_in[2];
    const float* graph_h0= (const float*)d_in[3];
    const float* graph_c0= (const float*)d_in[4];
    const float* W_dyn   = (const float*)d_in[5];
    const float* b_dyn   = (const float*)d_in[6];
    const float* W_gemb  = (const float*)d_in[7];
    const float* b_gemb  = (const float*)d_in[8];
    const float* Wih_g   = (const float*)d_in[9];
    const float* Whh_g   = (const float*)d_in[10];
    const float* bih_g   = (const float*)d_in[11];
    const float* bhh_g   = (const float*)d_in[12];
    const float* w_graph = (const float*)d_in[13];
    const float* Wih_c   = (const float*)d_in[14];
    const float* Whh_c   = (const float*)d_in[15];
    const float* bih_c   = (const float*)d_in[16];
    const float* bhh_c   = (const float*)d_in[17];
    const float* W_out   = (const float*)d_in[18];
    const float* b_out   = (const float*)d_in[19];

    float* out0 = (float*)d_out;                        // [S][N][5]
    float* chf = out0 + (size_t)Sx * Nx * OUTx;         // [N][64]
    float* ccf = chf + (size_t)Nx * 64;
    float* ghf = ccf + (size_t)Nx * 64;
    float* gcf = ghf + (size_t)Nx * 64;

    char* w = (char*)d_ws;
    float*  partials= (float*)w;                  w += (size_t)Sx * GRIDA * 64 * 4; // 4 MB
    float*  bias_all= (float*)w;                  w += Sx * 256 * 4;
    ushort* Wg      = (ushort*)w;                 w += 256 * KG * 2;
    ushort* Wc      = (ushort*)w;                 w += 256 * KC * 2;
    ushort* WoB     = (ushort*)w;                 w += 16 * 64 * 2;
    float*  Wfold2  = (float*)w;                  w += 64 * 256 * 4;
    float*  bsum_g  = (float*)w;                  w += 256 * 4;
    float*  bC0     = (float*)w;                  w += 256 * 4;

    k_prep<<<64, 256, 0, stream>>>(Wih_g, Whh_g, bih_g, bhh_g, w_graph,
                                   Wih_c, Whh_c, bih_c, bhh_c, W_out,
                                   Wg, Wc, WoB, Wfold2, bsum_g, bC0);

    k_graph_all<<<GRIDA, TPB, 0, stream>>>(input, graph_h0, graph_c0,
                                           W_gemb, b_gemb, Wg, bsum_g,
                                           partials, ghf, gcf);

    k_bias<<<Sx, 256, 0, stream>>>(partials, Wfold2, bC0, bias_all);

    k_cell_all<<<GRIDA, TPB, 0, stream>>>(input, graph_h0, graph_c0,
                                          cell_h0, cell_c0,
                                          W_gemb, b_gemb, Wg, bsum_g,
                                          W_dyn, b_dyn, Wc, bias_all,
                                          WoB, b_out,
                                          out0, chf, ccf);
}

// Round 12
// 681.978 us; speedup vs baseline: 6.2685x; 1.2300x over previous
//
#include <hip/hip_runtime.h>

// GraphLSTM v8 = round-11 + gh pass-through when ws_size permits.
// A) k_graph_all: graph LSTM all 32 steps; optionally STORES gh(t) bf16
//    ([S][N][64], 256 MB) -- it already has the exact layout in registers.
// B) k_bias: partials -> bias_all.
// C) two variants chosen by ws_size (deterministic):
//    k_cell_pt: reads ghb (no graph recompute: -48 MFMA, -half the
//               transcendentals, -half the LDS transpose traffic)
//    k_cell_rc: round-11 recompute path (fallback, proven).
// Numerics bit-identical either way (C consumes the same f2b(h2) bits).

#define Sx    32
#define Nx    65536
#define OUTx  5
#define KG    96              // graph gates K: [gemb(32) | gh(64)]
#define KC    160             // cell gates K:  [dyn(32) | gh(64) | ch(64)]
#define LWG   104             // lds row stride (ushorts) for Wg (96+8 pad)
#define LWC   168             // lds row stride (ushorts) for Wc (160+8 pad)
#define GRIDA 512             // blocks for A and C
#define TPB   512             // 8 waves x 16 nodes = 128 nodes/block

typedef __attribute__((ext_vector_type(4))) float f32x4;
typedef __attribute__((ext_vector_type(8))) short bf16x8;
typedef unsigned short ushort;
typedef unsigned int uint;

__device__ __forceinline__ float sigm(float x) {
    return __builtin_amdgcn_rcpf(1.f + __expf(-x));
}
__device__ __forceinline__ float tanh_fast(float x) {
    return fmaf(-2.f, __builtin_amdgcn_rcpf(1.f + __expf(2.f * x)), 1.f);
}
__device__ __forceinline__ ushort f2b(float x) {
    uint u = __float_as_uint(x);
    u += 0x7fffu + ((u >> 16) & 1u);   // RNE
    return (ushort)(u >> 16);
}

// ---------------- weight prep (once per launch, parallel) ----------------
__global__ __launch_bounds__(256) void k_prep(
    const float* __restrict__ Wih_g, const float* __restrict__ Whh_g,
    const float* __restrict__ bih_g, const float* __restrict__ bhh_g,
    const float* __restrict__ wgr,
    const float* __restrict__ Wih_c, const float* __restrict__ Whh_c,
    const float* __restrict__ bih_c, const float* __restrict__ bhh_c,
    const float* __restrict__ Wout,
    ushort* __restrict__ Wg, ushort* __restrict__ Wc,
    ushort* __restrict__ WoB,
    float* __restrict__ Wfold2,
    float* __restrict__ bsum_g, float* __restrict__ bC0)
{
    const int tid = blockIdx.x * 256 + threadIdx.x;
    const int nt = gridDim.x * 256;
    for (int idx = tid; idx < 256 * KG; idx += nt) {
        int col = idx / KG, k = idx % KG;
        float v = (k < 32) ? Wih_g[col * 32 + k] : Whh_g[col * 64 + (k - 32)];
        Wg[idx] = f2b(v);
    }
    for (int idx = tid; idx < 256 * KC; idx += nt) {
        int col = idx / KC, k = idx % KC;
        float v;
        if (k < 32) v = Wih_c[col * 64 + k];
        else if (k < 96) {
            int d = k - 32; float a = 0.f;
            for (int j = 0; j < 32; ++j)
                a = fmaf(wgr[d * 32 + j], Wih_c[col * 64 + 32 + j], a);
            v = -a;   // per-node part of loo is (-gh)
        } else v = Whh_c[col * 64 + (k - 96)];
        Wc[idx] = f2b(v);
    }
    for (int idx = tid; idx < 16 * 64; idx += nt) {
        int col = idx >> 6, k = idx & 63;
        WoB[idx] = (col < OUTx) ? f2b(Wout[col * 64 + k]) : (ushort)0;
    }
    for (int idx = tid; idx < 64 * 256; idx += nt) {
        int k = idx >> 8, col = idx & 255;
        float a = 0.f;
        for (int j = 0; j < 32; ++j)
            a = fmaf(wgr[k * 32 + j], Wih_c[col * 64 + 32 + j], a);
        Wfold2[idx] = a;
    }
    if (tid < 256) {
        bsum_g[tid] = bih_g[tid] + bhh_g[tid];
        bC0[tid]    = bih_c[tid] + bhh_c[tid];
    }
}

// ---------------- A: graph LSTM, all steps -------------------------------
__global__ __launch_bounds__(TPB, 2) void k_graph_all(
    const float* __restrict__ input,               // [S][N][2]
    const float* __restrict__ gh0, const float* __restrict__ gc0,
    const float* __restrict__ Wge, const float* __restrict__ bge,
    const ushort* __restrict__ Wg, const float* __restrict__ bsum_g,
    float* __restrict__ partials,                  // [S][GRIDA][64]
    ushort* __restrict__ ghb,                      // [S][N][64] or null
    float* __restrict__ ghf, float* __restrict__ gcf)
{
    const int tid = threadIdx.x;
    const int wave = tid >> 6, lane = tid & 63;
    const int c = lane & 15, g4 = lane >> 4;
    const int nb = blockIdx.x * 128 + wave * 16;
    const int na = nb + c;

    __shared__ __align__(16) ushort lWg[256 * LWG];
    __shared__ __align__(16) ushort t_lds[8][16][72];
    __shared__ float wsum[2][8][64];

    {
        const uint* src = (const uint*)Wg;
        uint* dst = (uint*)lWg;
        for (int i = tid; i < 256 * (KG / 2); i += TPB)
            dst[(i / (KG / 2)) * (LWG / 2) + (i % (KG / 2))] = src[i];
    }
    __syncthreads();

    float gcr[4][4];
#pragma unroll
    for (int q = 0; q < 4; ++q)
#pragma unroll
        for (int r = 0; r < 4; ++r)
            gcr[q][r] = gc0[(nb + 4 * g4 + r) * 64 + 16 * q + c];
    bf16x8 agh0, agh1;
#pragma unroll
    for (int j = 0; j < 8; ++j) {
        agh0[j] = (short)f2b(gh0[na * 64 + g4 * 8 + j]);
        agh1[j] = (short)f2b(gh0[na * 64 + 32 + g4 * 8 + j]);
    }

#pragma unroll 1
    for (int t = 0; t < Sx; ++t) {
        const float* frame = input + (size_t)t * Nx * 2;
        const float f0 = frame[2 * na], f1 = frame[2 * na + 1];
        const int lastt = (t == Sx - 1);
        bf16x8 a0;
#pragma unroll
        for (int j = 0; j < 8; ++j) {
            const int k = g4 * 8 + j;
            float v = fmaf(f1, Wge[2 * k + 1], fmaf(f0, Wge[2 * k], bge[k]));
            a0[j] = (short)f2b(fmaxf(v, 0.f));
        }
        float hsq[4];
#pragma unroll 1
        for (int q = 0; q < 4; ++q) {
            f32x4 acc[4];
#pragma unroll
            for (int g = 0; g < 4; ++g) {
                acc[g] = (f32x4){0.f, 0.f, 0.f, 0.f};
                const ushort* wp = lWg + (16 * (4 * g + q) + c) * LWG + g4 * 8;
                bf16x8 b0 = *(const bf16x8*)(wp);
                bf16x8 b1 = *(const bf16x8*)(wp + 32);
                bf16x8 b2 = *(const bf16x8*)(wp + 64);
                acc[g] = __builtin_amdgcn_mfma_f32_16x16x32_bf16(a0,   b0, acc[g], 0, 0, 0);
                acc[g] = __builtin_amdgcn_mfma_f32_16x16x32_bf16(agh0, b1, acc[g], 0, 0, 0);
                acc[g] = __builtin_amdgcn_mfma_f32_16x16x32_bf16(agh1, b2, acc[g], 0, 0, 0);
            }
            const int d = 16 * q + c;
            const float bi = bsum_g[d], bf = bsum_g[64 + d],
                        bg = bsum_g[128 + d], bo = bsum_g[192 + d];
            float s_r = 0.f;
#pragma unroll
            for (int r = 0; r < 4; ++r) {
                const float ai = acc[0][r] + bi, af = acc[1][r] + bf,
                            ag = acc[2][r] + bg, ao = acc[3][r] + bo;
                const float c2 = fmaf(sigm(af), gcr[q][r], sigm(ai) * tanh_fast(ag));
                gcr[q][r] = c2;
                const float h2 = sigm(ao) * tanh_fast(c2);
                t_lds[wave][4 * g4 + r][16 * q + c] = f2b(h2);
                if (lastt) {
                    const int n = nb + 4 * g4 + r;
                    ghf[n * 64 + d] = h2;
                    gcf[n * 64 + d] = c2;
                }
                s_r += h2;
            }
            hsq[q] = s_r;
        }
#pragma unroll
        for (int q = 0; q < 4; ++q) {
            float v = hsq[q];
            v += __shfl_xor(v, 16);
            v += __shfl_xor(v, 32);
            hsq[q] = v;
        }
        if (g4 == 0) {
#pragma unroll
            for (int q = 0; q < 4; ++q) wsum[t & 1][wave][16 * q + c] = hsq[q];
        }
        __syncthreads();
        agh0 = *(const bf16x8*)(&t_lds[wave][c][g4 * 8]);        // gh(t)
        agh1 = *(const bf16x8*)(&t_lds[wave][c][32 + g4 * 8]);
        if (ghb) {   // publish gh(t): [N][64] layout, coalesced 16B stores
            ushort* gp = ghb + ((size_t)t * Nx + na) * 64 + g4 * 8;
            *(bf16x8*)(gp)      = agh0;
            *(bf16x8*)(gp + 32) = agh1;
        }
        if (tid < 64) {
            float a = 0.f;
#pragma unroll
            for (int w8 = 0; w8 < 8; ++w8) a += wsum[t & 1][w8][tid];
            partials[((size_t)t * GRIDA + blockIdx.x) * 64 + tid] = a;
        }
    }
}

// ---------------- B: per-step bias from partials ---------------------------
__global__ __launch_bounds__(256) void k_bias(
    const float* __restrict__ partials,   // [S][GRIDA][64]
    const float* __restrict__ Wfold2, const float* __restrict__ bC0,
    float* __restrict__ bias_all)         // [S][256]
{
    const int t = blockIdx.x, tid = threadIdx.x;
    __shared__ float red[4][64];
    __shared__ float S[64];
    const int d = tid & 63, j = tid >> 6;
    float a = 0.f;
    for (int b = j; b < GRIDA; b += 4)
        a += partials[((size_t)t * GRIDA + b) * 64 + d];
    red[j][d] = a;
    __syncthreads();
    if (tid < 64) S[tid] = red[0][tid] + red[1][tid] + red[2][tid] + red[3][tid];
    __syncthreads();
    float bv = bC0[tid];
#pragma unroll
    for (int k = 0; k < 64; ++k) bv = fmaf(S[k], Wfold2[k * 256 + tid], bv);
    bias_all[t * 256 + tid] = bv;
}

// ---------------- C (pass-through): cell LSTM only ------------------------
__global__ __launch_bounds__(TPB, 2) void k_cell_pt(
    const float* __restrict__ input,               // [S][N][2]
    const ushort* __restrict__ ghb,                // [S][N][64]
    const float* __restrict__ ch0, const float* __restrict__ cc0,
    const float* __restrict__ Wdy, const float* __restrict__ bdy,
    const ushort* __restrict__ Wc, const float* __restrict__ bias_all,
    const ushort* __restrict__ WoB, const float* __restrict__ bo5,
    float* __restrict__ out0,                      // [S][N][5]
    float* __restrict__ chf, float* __restrict__ ccf)
{
    const int tid = threadIdx.x;
    const int wave = tid >> 6, lane = tid & 63;
    const int c = lane & 15, g4 = lane >> 4;
    const int nb = blockIdx.x * 128 + wave * 16;
    const int na = nb + c;

    __shared__ __align__(16) ushort lWc[256 * LWC];      // 86 KB
    __shared__ __align__(16) ushort t_lds[8][16][72];    // 18.4 KB

    {
        const uint* src2 = (const uint*)Wc;
        uint* dst2 = (uint*)lWc;
        for (int i = tid; i < 256 * (KC / 2); i += TPB)
            dst2[(i / (KC / 2)) * (LWC / 2) + (i % (KC / 2))] = src2[i];
    }
    __syncthreads();

    float ccr[4][4];
#pragma unroll
    for (int q = 0; q < 4; ++q)
#pragma unroll
        for (int r = 0; r < 4; ++r)
            ccr[q][r] = cc0[(nb + 4 * g4 + r) * 64 + 16 * q + c];
    bf16x8 ach0, ach1;
#pragma unroll
    for (int j = 0; j < 8; ++j) {
        ach0[j] = (short)f2b(ch0[na * 64 + g4 * 8 + j]);
        ach1[j] = (short)f2b(ch0[na * 64 + 32 + g4 * 8 + j]);
    }
    bf16x8 woB0 = *(const bf16x8*)(WoB + c * 64 + g4 * 8);
    bf16x8 woB1 = *(const bf16x8*)(WoB + c * 64 + 32 + g4 * 8);
    const float bo_c = (c < OUTx) ? bo5[c] : 0.f;

#pragma unroll 1
    for (int t = 0; t < Sx; ++t) {
        const float* frame = input + (size_t)t * Nx * 2;
        const float f0 = frame[2 * na], f1 = frame[2 * na + 1];
        const int lastt = (t == Sx - 1);

        // gh(t) from A (same bits the recompute would produce)
        const ushort* gp = ghb + ((size_t)t * Nx + na) * 64 + g4 * 8;
        bf16x8 agh0 = *(const bf16x8*)(gp);
        bf16x8 agh1 = *(const bf16x8*)(gp + 32);

        bf16x8 a0c;
#pragma unroll
        for (int j = 0; j < 8; ++j) {
            const int k = g4 * 8 + j;
            float v = fmaf(f1, Wdy[2 * k + 1], fmaf(f0, Wdy[2 * k], bdy[k]));
            a0c[j] = (short)f2b(fmaxf(v, 0.f));
        }
#pragma unroll 1
        for (int q = 0; q < 4; ++q) {
            f32x4 acc[4];
#pragma unroll
            for (int g = 0; g < 4; ++g) {
                acc[g] = (f32x4){0.f, 0.f, 0.f, 0.f};
                const ushort* wp = lWc + (16 * (4 * g + q) + c) * LWC + g4 * 8;
                bf16x8 b0 = *(const bf16x8*)(wp);
                bf16x8 b1 = *(const bf16x8*)(wp + 32);
                bf16x8 b2 = *(const bf16x8*)(wp + 64);
                bf16x8 b3 = *(const bf16x8*)(wp + 96);
                bf16x8 b4 = *(const bf16x8*)(wp + 128);
                acc[g] = __builtin_amdgcn_mfma_f32_16x16x32_bf16(a0c,  b0, acc[g], 0, 0, 0);
                acc[g] = __builtin_amdgcn_mfma_f32_16x16x32_bf16(agh0, b1, acc[g], 0, 0, 0);
                acc[g] = __builtin_amdgcn_mfma_f32_16x16x32_bf16(agh1, b2, acc[g], 0, 0, 0);
                acc[g] = __builtin_amdgcn_mfma_f32_16x16x32_bf16(ach0, b3, acc[g], 0, 0, 0);
                acc[g] = __builtin_amdgcn_mfma_f32_16x16x32_bf16(ach1, b4, acc[g], 0, 0, 0);
            }
            const int d = 16 * q + c;
            const float bi = bias_all[t * 256 + d],
                        bf = bias_all[t * 256 + 64 + d],
                        bg = bias_all[t * 256 + 128 + d],
                        bov = bias_all[t * 256 + 192 + d];
#pragma unroll
            for (int r = 0; r < 4; ++r) {
                const float ai = acc[0][r] + bi, af = acc[1][r] + bf,
                            ag = acc[2][r] + bg, ao = acc[3][r] + bov;
                const float c2 = fmaf(sigm(af), ccr[q][r], sigm(ai) * tanh_fast(ag));
                ccr[q][r] = c2;
                const float h2 = sigm(ao) * tanh_fast(c2);
                t_lds[wave][4 * g4 + r][16 * q + c] = f2b(h2);
                if (lastt) {
                    const int n = nb + 4 * g4 + r;
                    chf[n * 64 + d] = h2;
                    ccf[n * 64 + d] = c2;
                }
            }
        }
        ach0 = *(const bf16x8*)(&t_lds[wave][c][g4 * 8]);        // ch(t)
        ach1 = *(const bf16x8*)(&t_lds[wave][c][32 + g4 * 8]);

        {
            f32x4 oa = (f32x4){0.f, 0.f, 0.f, 0.f};
            oa = __builtin_amdgcn_mfma_f32_16x16x32_bf16(ach0, woB0, oa, 0, 0, 0);
            oa = __builtin_amdgcn_mfma_f32_16x16x32_bf16(ach1, woB1, oa, 0, 0, 0);
            if (c < OUTx) {
                float* outp = out0 + (size_t)t * Nx * OUTx;
#pragma unroll
                for (int r = 0; r < 4; ++r)
                    outp[(nb + 4 * g4 + r) * OUTx + c] = oa[r] + bo_c;
            }
        }
    }
}

// ---------------- C (fallback): graph recompute + cell (round-11) ---------
__global__ __launch_bounds__(TPB, 2) void k_cell_rc(
    const float* __restrict__ input,
    const float* __restrict__ gh0, const float* __restrict__ gc0,
    const float* __restrict__ ch0, const float* __restrict__ cc0,
    const float* __restrict__ Wge, const float* __restrict__ bge,
    const ushort* __restrict__ Wg, const float* __restrict__ bsum_g,
    const float* __restrict__ Wdy, const float* __restrict__ bdy,
    const ushort* __restrict__ Wc, const float* __restrict__ bias_all,
    const ushort* __restrict__ WoB, const float* __restrict__ bo5,
    float* __restrict__ out0,
    float* __restrict__ chf, float* __restrict__ ccf)
{
    const int tid = threadIdx.x;
    const int wave = tid >> 6, lane = tid & 63;
    const int c = lane & 15, g4 = lane >> 4;
    const int nb = blockIdx.x * 128 + wave * 16;
    const int na = nb + c;

    __shared__ __align__(16) ushort lWg[256 * LWG];
    __shared__ __align__(16) ushort lWc[256 * LWC];
    __shared__ __align__(16) ushort t_lds[8][16][72];

    {
        const uint* src = (const uint*)Wg;
        uint* dst = (uint*)lWg;
        for (int i = tid; i < 256 * (KG / 2); i += TPB)
            dst[(i / (KG / 2)) * (LWG / 2) + (i % (KG / 2))] = src[i];
        const uint* src2 = (const uint*)Wc;
        uint* dst2 = (uint*)lWc;
        for (int i = tid; i < 256 * (KC / 2); i += TPB)
            dst2[(i / (KC / 2)) * (LWC / 2) + (i % (KC / 2))] = src2[i];
    }
    __syncthreads();

    float gcr[4][4], ccr[4][4];
#pragma unroll
    for (int q = 0; q < 4; ++q)
#pragma unroll
        for (int r = 0; r < 4; ++r) {
            const int n = nb + 4 * g4 + r, d = 16 * q + c;
            gcr[q][r] = gc0[n * 64 + d];
            ccr[q][r] = cc0[n * 64 + d];
        }
    bf16x8 agh0, agh1, ach0, ach1;
#pragma unroll
    for (int j = 0; j < 8; ++j) {
        agh0[j] = (short)f2b(gh0[na * 64 + g4 * 8 + j]);
        agh1[j] = (short)f2b(gh0[na * 64 + 32 + g4 * 8 + j]);
        ach0[j] = (short)f2b(ch0[na * 64 + g4 * 8 + j]);
        ach1[j] = (short)f2b(ch0[na * 64 + 32 + g4 * 8 + j]);
    }
    bf16x8 woB0 = *(const bf16x8*)(WoB + c * 64 + g4 * 8);
    bf16x8 woB1 = *(const bf16x8*)(WoB + c * 64 + 32 + g4 * 8);
    const float bo_c = (c < OUTx) ? bo5[c] : 0.f;

#pragma unroll 1
    for (int t = 0; t < Sx; ++t) {
        const float* frame = input + (size_t)t * Nx * 2;
        const float f0 = frame[2 * na], f1 = frame[2 * na + 1];
        const int lastt = (t == Sx - 1);

        bf16x8 a0;
#pragma unroll
        for (int j = 0; j < 8; ++j) {
            const int k = g4 * 8 + j;
            float v = fmaf(f1, Wge[2 * k + 1], fmaf(f0, Wge[2 * k], bge[k]));
            a0[j] = (short)f2b(fmaxf(v, 0.f));
        }
#pragma unroll 1
        for (int q = 0; q < 4; ++q) {
            f32x4 acc[4];
#pragma unroll
            for (int g = 0; g < 4; ++g) {
                acc[g] = (f32x4){0.f, 0.f, 0.f, 0.f};
                const ushort* wp = lWg + (16 * (4 * g + q) + c) * LWG + g4 * 8;
                bf16x8 b0 = *(const bf16x8*)(wp);
                bf16x8 b1 = *(const bf16x8*)(wp + 32);
                bf16x8 b2 = *(const bf16x8*)(wp + 64);
                acc[g] = __builtin_amdgcn_mfma_f32_16x16x32_bf16(a0,   b0, acc[g], 0, 0, 0);
                acc[g] = __builtin_amdgcn_mfma_f32_16x16x32_bf16(agh0, b1, acc[g], 0, 0, 0);
                acc[g] = __builtin_amdgcn_mfma_f32_16x16x32_bf16(agh1, b2, acc[g], 0, 0, 0);
            }
            const int d = 16 * q + c;
            const float bi = bsum_g[d], bf = bsum_g[64 + d],
                        bg = bsum_g[128 + d], bo = bsum_g[192 + d];
#pragma unroll
            for (int r = 0; r < 4; ++r) {
                const float ai = acc[0][r] + bi, af = acc[1][r] + bf,
                            ag = acc[2][r] + bg, ao = acc[3][r] + bo;
                const float c2 = fmaf(sigm(af), gcr[q][r], sigm(ai) * tanh_fast(ag));
                gcr[q][r] = c2;
                const float h2 = sigm(ao) * tanh_fast(c2);
                t_lds[wave][4 * g4 + r][16 * q + c] = f2b(h2);
            }
        }
        agh0 = *(const bf16x8*)(&t_lds[wave][c][g4 * 8]);
        agh1 = *(const bf16x8*)(&t_lds[wave][c][32 + g4 * 8]);

        bf16x8 a0c;
#pragma unroll
        for (int j = 0; j < 8; ++j) {
            const int k = g4 * 8 + j;
            float v = fmaf(f1, Wdy[2 * k + 1], fmaf(f0, Wdy[2 * k], bdy[k]));
            a0c[j] = (short)f2b(fmaxf(v, 0.f));
        }
#pragma unroll 1
        for (int q = 0; q < 4; ++q) {
            f32x4 acc[4];
#pragma unroll
            for (int g = 0; g < 4; ++g) {
                acc[g] = (f32x4){0.f, 0.f, 0.f, 0.f};
                const ushort* wp = lWc + (16 * (4 * g + q) + c) * LWC + g4 * 8;
                bf16x8 b0 = *(const bf16x8*)(wp);
                bf16x8 b1 = *(const bf16x8*)(wp + 32);
                bf16x8 b2 = *(const bf16x8*)(wp + 64);
                bf16x8 b3 = *(const bf16x8*)(wp + 96);
                bf16x8 b4 = *(const bf16x8*)(wp + 128);
                acc[g] = __builtin_amdgcn_mfma_f32_16x16x32_bf16(a0c,  b0, acc[g], 0, 0, 0);
                acc[g] = __builtin_amdgcn_mfma_f32_16x16x32_bf16(agh0, b1, acc[g], 0, 0, 0);
                acc[g] = __builtin_amdgcn_mfma_f32_16x16x32_bf16(agh1, b2, acc[g], 0, 0, 0);
                acc[g] = __builtin_amdgcn_mfma_f32_16x16x32_bf16(ach0, b3, acc[g], 0, 0, 0);
                acc[g] = __builtin_amdgcn_mfma_f32_16x16x32_bf16(ach1, b4, acc[g], 0, 0, 0);
            }
            const int d = 16 * q + c;
            const float bi = bias_all[t * 256 + d],
                        bf = bias_all[t * 256 + 64 + d],
                        bg = bias_all[t * 256 + 128 + d],
                        bov = bias_all[t * 256 + 192 + d];
#pragma unroll
            for (int r = 0; r < 4; ++r) {
                const float ai = acc[0][r] + bi, af = acc[1][r] + bf,
                            ag = acc[2][r] + bg, ao = acc[3][r] + bov;
                const float c2 = fmaf(sigm(af), ccr[q][r], sigm(ai) * tanh_fast(ag));
                ccr[q][r] = c2;
                const float h2 = sigm(ao) * tanh_fast(c2);
                t_lds[wave][4 * g4 + r][16 * q + c] = f2b(h2);
                if (lastt) {
                    const int n = nb + 4 * g4 + r;
                    chf[n * 64 + d] = h2;
                    ccf[n * 64 + d] = c2;
                }
            }
        }
        ach0 = *(const bf16x8*)(&t_lds[wave][c][g4 * 8]);
        ach1 = *(const bf16x8*)(&t_lds[wave][c][32 + g4 * 8]);

        {
            f32x4 oa = (f32x4){0.f, 0.f, 0.f, 0.f};
            oa = __builtin_amdgcn_mfma_f32_16x16x32_bf16(ach0, woB0, oa, 0, 0, 0);
            oa = __builtin_amdgcn_mfma_f32_16x16x32_bf16(ach1, woB1, oa, 0, 0, 0);
            if (c < OUTx) {
                float* outp = out0 + (size_t)t * Nx * OUTx;
#pragma unroll
                for (int r = 0; r < 4; ++r)
                    outp[(nb + 4 * g4 + r) * OUTx + c] = oa[r] + bo_c;
            }
        }
    }
}

extern "C" void kernel_launch(void* const* d_in, const int* in_sizes, int n_in,
                              void* d_out, int out_size, void* d_ws, size_t ws_size,
                              hipStream_t stream) {
    const float* input   = (const float*)d_in[0];   // [S][N][2]
    const float* cell_h0 = (const float*)d_in[1];
    const float* cell_c0 = (const float*)d_in[2];
    const float* graph_h0= (const float*)d_in[3];
    const float* graph_c0= (const float*)d_in[4];
    const float* W_dyn   = (const float*)d_in[5];
    const float* b_dyn   = (const float*)d_in[6];
    const float* W_gemb  = (const float*)d_in[7];
    const float* b_gemb  = (const float*)d_in[8];
    const float* Wih_g   = (const float*)d_in[9];
    const float* Whh_g   = (const float*)d_in[10];
    const float* bih_g   = (const float*)d_in[11];
    const float* bhh_g   = (const float*)d_in[12];
    const float* w_graph = (const float*)d_in[13];
    const float* Wih_c   = (const float*)d_in[14];
    const float* Whh_c   = (const float*)d_in[15];
    const float* bih_c   = (const float*)d_in[16];
    const float* bhh_c   = (const float*)d_in[17];
    const float* W_out   = (const float*)d_in[18];
    const float* b_out   = (const float*)d_in[19];

    float* out0 = (float*)d_out;                        // [S][N][5]
    float* chf = out0 + (size_t)Sx * Nx * OUTx;         // [N][64]
    float* ccf = chf + (size_t)Nx * 64;
    float* ghf = ccf + (size_t)Nx * 64;
    float* gcf = ghf + (size_t)Nx * 64;

    size_t off = 0;
    char* base = (char*)d_ws;
    float*  partials= (float*)(base + off); off += (size_t)Sx * GRIDA * 64 * 4;
    float*  bias_all= (float*)(base + off); off += (size_t)Sx * 256 * 4;
    ushort* Wg      = (ushort*)(base + off); off += 256 * KG * 2;
    ushort* Wc      = (ushort*)(base + off); off += 256 * KC * 2;
    ushort* WoB     = (ushort*)(base + off); off += 16 * 64 * 2;
    float*  Wfold2  = (float*)(base + off); off += 64 * 256 * 4;
    float*  bsum_g  = (float*)(base + off); off += 256 * 4;
    float*  bC0     = (float*)(base + off); off += 256 * 4;
    off = (off + 255) & ~(size_t)255;
    const size_t ghb_bytes = (size_t)Sx * Nx * 64 * 2;   // 256 MB
    const bool use_pt = (ws_size >= off + ghb_bytes);
    ushort* ghb = use_pt ? (ushort*)(base + off) : (ushort*)nullptr;

    k_prep<<<64, 256, 0, stream>>>(Wih_g, Whh_g, bih_g, bhh_g, w_graph,
                                   Wih_c, Whh_c, bih_c, bhh_c, W_out,
                                   Wg, Wc, WoB, Wfold2, bsum_g, bC0);

    k_graph_all<<<GRIDA, TPB, 0, stream>>>(input, graph_h0, graph_c0,
                                           W_gemb, b_gemb, Wg, bsum_g,
                                           partials, ghb, ghf, gcf);

    k_bias<<<Sx, 256, 0, stream>>>(partials, Wfold2, bC0, bias_all);

    if (use_pt) {
        k_cell_pt<<<GRIDA, TPB, 0, stream>>>(input, ghb, cell_h0, cell_c0,
                                             W_dyn, b_dyn, Wc, bias_all,
                                             WoB, b_out, out0, chf, ccf);
    } else {
        k_cell_rc<<<GRIDA, TPB, 0, stream>>>(input, graph_h0, graph_c0,
                                             cell_h0, cell_c0,
                                             W_gemb, b_gemb, Wg, bsum_g,
                                             W_dyn, b_dyn, Wc, bias_all,
                                             WoB, b_out, out0, chf, ccf);
    }
}

// Round 13
// 594.746 us; speedup vs baseline: 7.1880x; 1.1467x over previous
//
#include <hip/hip_runtime.h>

// GraphLSTM v9 = round-12 + 16-wave blocks (2x TLP) + t_lds XOR swizzle.
// Round-12 counters: k_cell_pt VALUBusy 53%, MfmaUtil 19%, Occupancy 21.8%
// (LDS-capped 8 waves/CU), 43M LDS bank conflicts (4-way on transpose write).
// 1) TPB 512->1024, GRID 512->256: same LDS now hosts 16 waves/CU (4/SIMD).
// 2) t_lds store at col^(((row>>2)&3)<<4): write banks spread over all 32,
//    reads stay b128-aligned (bits 4-5 flip only). Values bit-identical.
// Fallback k_cell_rc (no-ghb path) kept verbatim at 512 threads.

#define Sx    32
#define Nx    65536
#define OUTx  5
#define KG    96              // graph gates K: [gemb(32) | gh(64)]
#define KC    160             // cell gates K:  [dyn(32) | gh(64) | ch(64)]
#define LWG   104             // lds row stride (ushorts) for Wg (96+8 pad)
#define LWC   168             // lds row stride (ushorts) for Wc (160+8 pad)
#define GRIDA 256             // blocks for A and C-pt (16 waves each)
#define TPB   1024            // 16 waves x 16 nodes = 256 nodes/block
#define GRIDF 512             // fallback k_cell_rc geometry (8 waves)
#define TPBF  512

typedef __attribute__((ext_vector_type(4))) float f32x4;
typedef __attribute__((ext_vector_type(8))) short bf16x8;
typedef unsigned short ushort;
typedef unsigned int uint;

__device__ __forceinline__ float sigm(float x) {
    return __builtin_amdgcn_rcpf(1.f + __expf(-x));
}
__device__ __forceinline__ float tanh_fast(float x) {
    return fmaf(-2.f, __builtin_amdgcn_rcpf(1.f + __expf(2.f * x)), 1.f);
}
__device__ __forceinline__ ushort f2b(float x) {
    uint u = __float_as_uint(x);
    u += 0x7fffu + ((u >> 16) & 1u);   // RNE
    return (ushort)(u >> 16);
}
// transpose-tile swizzle: store logical (row,col) at col'(row,col).
// Flips only bits 4-5 of col -> 8-aligned b128 blocks stay contiguous.
__device__ __forceinline__ int swz(int row, int col) {
    return col ^ (((row >> 2) & 3) << 4);
}

// ---------------- weight prep (once per launch, parallel) ----------------
__global__ __launch_bounds__(256) void k_prep(
    const float* __restrict__ Wih_g, const float* __restrict__ Whh_g,
    const float* __restrict__ bih_g, const float* __restrict__ bhh_g,
    const float* __restrict__ wgr,
    const float* __restrict__ Wih_c, const float* __restrict__ Whh_c,
    const float* __restrict__ bih_c, const float* __restrict__ bhh_c,
    const float* __restrict__ Wout,
    ushort* __restrict__ Wg, ushort* __restrict__ Wc,
    ushort* __restrict__ WoB,
    float* __restrict__ Wfold2,
    float* __restrict__ bsum_g, float* __restrict__ bC0)
{
    const int tid = blockIdx.x * 256 + threadIdx.x;
    const int nt = gridDim.x * 256;
    for (int idx = tid; idx < 256 * KG; idx += nt) {
        int col = idx / KG, k = idx % KG;
        float v = (k < 32) ? Wih_g[col * 32 + k] : Whh_g[col * 64 + (k - 32)];
        Wg[idx] = f2b(v);
    }
    for (int idx = tid; idx < 256 * KC; idx += nt) {
        int col = idx / KC, k = idx % KC;
        float v;
        if (k < 32) v = Wih_c[col * 64 + k];
        else if (k < 96) {
            int d = k - 32; float a = 0.f;
            for (int j = 0; j < 32; ++j)
                a = fmaf(wgr[d * 32 + j], Wih_c[col * 64 + 32 + j], a);
            v = -a;   // per-node part of loo is (-gh)
        } else v = Whh_c[col * 64 + (k - 96)];
        Wc[idx] = f2b(v);
    }
    for (int idx = tid; idx < 16 * 64; idx += nt) {
        int col = idx >> 6, k = idx & 63;
        WoB[idx] = (col < OUTx) ? f2b(Wout[col * 64 + k]) : (ushort)0;
    }
    for (int idx = tid; idx < 64 * 256; idx += nt) {
        int k = idx >> 8, col = idx & 255;
        float a = 0.f;
        for (int j = 0; j < 32; ++j)
            a = fmaf(wgr[k * 32 + j], Wih_c[col * 64 + 32 + j], a);
        Wfold2[idx] = a;
    }
    if (tid < 256) {
        bsum_g[tid] = bih_g[tid] + bhh_g[tid];
        bC0[tid]    = bih_c[tid] + bhh_c[tid];
    }
}

// ---------------- A: graph LSTM, all steps -------------------------------
__global__ __launch_bounds__(TPB, 2) void k_graph_all(
    const float* __restrict__ input,               // [S][N][2]
    const float* __restrict__ gh0, const float* __restrict__ gc0,
    const float* __restrict__ Wge, const float* __restrict__ bge,
    const ushort* __restrict__ Wg, const float* __restrict__ bsum_g,
    float* __restrict__ partials,                  // [S][GRIDA][64]
    ushort* __restrict__ ghb,                      // [S][N][64] or null
    float* __restrict__ ghf, float* __restrict__ gcf)
{
    const int tid = threadIdx.x;
    const int wave = tid >> 6, lane = tid & 63;
    const int c = lane & 15, g4 = lane >> 4;
    const int nb = blockIdx.x * 256 + wave * 16;
    const int na = nb + c;

    __shared__ __align__(16) ushort lWg[256 * LWG];      // 53.2 KB
    __shared__ __align__(16) ushort t_lds[16][16][72];   // 36.9 KB
    __shared__ float wsum[2][16][64];                    //  8.2 KB

    {
        const uint* src = (const uint*)Wg;
        uint* dst = (uint*)lWg;
        for (int i = tid; i < 256 * (KG / 2); i += TPB)
            dst[(i / (KG / 2)) * (LWG / 2) + (i % (KG / 2))] = src[i];
    }
    __syncthreads();

    float gcr[4][4];
#pragma unroll
    for (int q = 0; q < 4; ++q)
#pragma unroll
        for (int r = 0; r < 4; ++r)
            gcr[q][r] = gc0[(nb + 4 * g4 + r) * 64 + 16 * q + c];
    bf16x8 agh0, agh1;
#pragma unroll
    for (int j = 0; j < 8; ++j) {
        agh0[j] = (short)f2b(gh0[na * 64 + g4 * 8 + j]);
        agh1[j] = (short)f2b(gh0[na * 64 + 32 + g4 * 8 + j]);
    }

#pragma unroll 1
    for (int t = 0; t < Sx; ++t) {
        const float* frame = input + (size_t)t * Nx * 2;
        const float f0 = frame[2 * na], f1 = frame[2 * na + 1];
        const int lastt = (t == Sx - 1);
        bf16x8 a0;
#pragma unroll
        for (int j = 0; j < 8; ++j) {
            const int k = g4 * 8 + j;
            float v = fmaf(f1, Wge[2 * k + 1], fmaf(f0, Wge[2 * k], bge[k]));
            a0[j] = (short)f2b(fmaxf(v, 0.f));
        }
        float hsq[4];
#pragma unroll 1
        for (int q = 0; q < 4; ++q) {
            f32x4 acc[4];
#pragma unroll
            for (int g = 0; g < 4; ++g) {
                acc[g] = (f32x4){0.f, 0.f, 0.f, 0.f};
                const ushort* wp = lWg + (16 * (4 * g + q) + c) * LWG + g4 * 8;
                bf16x8 b0 = *(const bf16x8*)(wp);
                bf16x8 b1 = *(const bf16x8*)(wp + 32);
                bf16x8 b2 = *(const bf16x8*)(wp + 64);
                acc[g] = __builtin_amdgcn_mfma_f32_16x16x32_bf16(a0,   b0, acc[g], 0, 0, 0);
                acc[g] = __builtin_amdgcn_mfma_f32_16x16x32_bf16(agh0, b1, acc[g], 0, 0, 0);
                acc[g] = __builtin_amdgcn_mfma_f32_16x16x32_bf16(agh1, b2, acc[g], 0, 0, 0);
            }
            const int d = 16 * q + c;
            const float bi = bsum_g[d], bf = bsum_g[64 + d],
                        bg = bsum_g[128 + d], bo = bsum_g[192 + d];
            float s_r = 0.f;
#pragma unroll
            for (int r = 0; r < 4; ++r) {
                const float ai = acc[0][r] + bi, af = acc[1][r] + bf,
                            ag = acc[2][r] + bg, ao = acc[3][r] + bo;
                const float c2 = fmaf(sigm(af), gcr[q][r], sigm(ai) * tanh_fast(ag));
                gcr[q][r] = c2;
                const float h2 = sigm(ao) * tanh_fast(c2);
                const int row = 4 * g4 + r;
                t_lds[wave][row][swz(row, 16 * q + c)] = f2b(h2);
                if (lastt) {
                    const int n = nb + row;
                    ghf[n * 64 + d] = h2;
                    gcf[n * 64 + d] = c2;
                }
                s_r += h2;
            }
            hsq[q] = s_r;
        }
#pragma unroll
        for (int q = 0; q < 4; ++q) {
            float v = hsq[q];
            v += __shfl_xor(v, 16);
            v += __shfl_xor(v, 32);
            hsq[q] = v;
        }
        if (g4 == 0) {
#pragma unroll
            for (int q = 0; q < 4; ++q) wsum[t & 1][wave][16 * q + c] = hsq[q];
        }
        __syncthreads();          // wsum visible (t_lds is same-wave only)
        agh0 = *(const bf16x8*)(&t_lds[wave][c][swz(c, g4 * 8)]);
        agh1 = *(const bf16x8*)(&t_lds[wave][c][swz(c, 32 + g4 * 8)]);
        if (ghb) {   // publish gh(t): [N][64] layout, coalesced 16B stores
            ushort* gp = ghb + ((size_t)t * Nx + na) * 64 + g4 * 8;
            *(bf16x8*)(gp)      = agh0;
            *(bf16x8*)(gp + 32) = agh1;
        }
        if (tid < 64) {
            float a = 0.f;
#pragma unroll
            for (int w8 = 0; w8 < 16; ++w8) a += wsum[t & 1][w8][tid];
            partials[((size_t)t * GRIDA + blockIdx.x) * 64 + tid] = a;
        }
    }
}

// ---------------- B: per-step bias from partials ---------------------------
__global__ __launch_bounds__(256) void k_bias(
    const float* __restrict__ partials,   // [S][GRIDA][64]
    const float* __restrict__ Wfold2, const float* __restrict__ bC0,
    float* __restrict__ bias_all)         // [S][256]
{
    const int t = blockIdx.x, tid = threadIdx.x;
    __shared__ float red[4][64];
    __shared__ float S[64];
    const int d = tid & 63, j = tid >> 6;
    float a = 0.f;
    for (int b = j; b < GRIDA; b += 4)
        a += partials[((size_t)t * GRIDA + b) * 64 + d];
    red[j][d] = a;
    __syncthreads();
    if (tid < 64) S[tid] = red[0][tid] + red[1][tid] + red[2][tid] + red[3][tid];
    __syncthreads();
    float bv = bC0[tid];
#pragma unroll
    for (int k = 0; k < 64; ++k) bv = fmaf(S[k], Wfold2[k * 256 + tid], bv);
    bias_all[t * 256 + tid] = bv;
}

// ---------------- C (pass-through): cell LSTM only ------------------------
__global__ __launch_bounds__(TPB, 2) void k_cell_pt(
    const float* __restrict__ input,               // [S][N][2]
    const ushort* __restrict__ ghb,                // [S][N][64]
    const float* __restrict__ ch0, const float* __restrict__ cc0,
    const float* __restrict__ Wdy, const float* __restrict__ bdy,
    const ushort* __restrict__ Wc, const float* __restrict__ bias_all,
    const ushort* __restrict__ WoB, const float* __restrict__ bo5,
    float* __restrict__ out0,                      // [S][N][5]
    float* __restrict__ chf, float* __restrict__ ccf)
{
    const int tid = threadIdx.x;
    const int wave = tid >> 6, lane = tid & 63;
    const int c = lane & 15, g4 = lane >> 4;
    const int nb = blockIdx.x * 256 + wave * 16;
    const int na = nb + c;

    __shared__ __align__(16) ushort lWc[256 * LWC];      // 86 KB
    __shared__ __align__(16) ushort t_lds[16][16][72];   // 36.9 KB

    {
        const uint* src2 = (const uint*)Wc;
        uint* dst2 = (uint*)lWc;
        for (int i = tid; i < 256 * (KC / 2); i += TPB)
            dst2[(i / (KC / 2)) * (LWC / 2) + (i % (KC / 2))] = src2[i];
    }
    __syncthreads();

    float ccr[4][4];
#pragma unroll
    for (int q = 0; q < 4; ++q)
#pragma unroll
        for (int r = 0; r < 4; ++r)
            ccr[q][r] = cc0[(nb + 4 * g4 + r) * 64 + 16 * q + c];
    bf16x8 ach0, ach1;
#pragma unroll
    for (int j = 0; j < 8; ++j) {
        ach0[j] = (short)f2b(ch0[na * 64 + g4 * 8 + j]);
        ach1[j] = (short)f2b(ch0[na * 64 + 32 + g4 * 8 + j]);
    }
    bf16x8 woB0 = *(const bf16x8*)(WoB + c * 64 + g4 * 8);
    bf16x8 woB1 = *(const bf16x8*)(WoB + c * 64 + 32 + g4 * 8);
    const float bo_c = (c < OUTx) ? bo5[c] : 0.f;

#pragma unroll 1
    for (int t = 0; t < Sx; ++t) {
        const float* frame = input + (size_t)t * Nx * 2;
        const float f0 = frame[2 * na], f1 = frame[2 * na + 1];
        const int lastt = (t == Sx - 1);

        // gh(t) from A (same bits the recompute would produce)
        const ushort* gp = ghb + ((size_t)t * Nx + na) * 64 + g4 * 8;
        bf16x8 agh0 = *(const bf16x8*)(gp);
        bf16x8 agh1 = *(const bf16x8*)(gp + 32);

        bf16x8 a0c;
#pragma unroll
        for (int j = 0; j < 8; ++j) {
            const int k = g4 * 8 + j;
            float v = fmaf(f1, Wdy[2 * k + 1], fmaf(f0, Wdy[2 * k], bdy[k]));
            a0c[j] = (short)f2b(fmaxf(v, 0.f));
        }
#pragma unroll 1
        for (int q = 0; q < 4; ++q) {
            f32x4 acc[4];
#pragma unroll
            for (int g = 0; g < 4; ++g) {
                acc[g] = (f32x4){0.f, 0.f, 0.f, 0.f};
                const ushort* wp = lWc + (16 * (4 * g + q) + c) * LWC + g4 * 8;
                bf16x8 b0 = *(const bf16x8*)(wp);
                bf16x8 b1 = *(const bf16x8*)(wp + 32);
                bf16x8 b2 = *(const bf16x8*)(wp + 64);
                bf16x8 b3 = *(const bf16x8*)(wp + 96);
                bf16x8 b4 = *(const bf16x8*)(wp + 128);
                acc[g] = __builtin_amdgcn_mfma_f32_16x16x32_bf16(a0c,  b0, acc[g], 0, 0, 0);
                acc[g] = __builtin_amdgcn_mfma_f32_16x16x32_bf16(agh0, b1, acc[g], 0, 0, 0);
                acc[g] = __builtin_amdgcn_mfma_f32_16x16x32_bf16(agh1, b2, acc[g], 0, 0, 0);
                acc[g] = __builtin_amdgcn_mfma_f32_16x16x32_bf16(ach0, b3, acc[g], 0, 0, 0);
                acc[g] = __builtin_amdgcn_mfma_f32_16x16x32_bf16(ach1, b4, acc[g], 0, 0, 0);
            }
            const int d = 16 * q + c;
            const float bi = bias_all[t * 256 + d],
                        bf = bias_all[t * 256 + 64 + d],
                        bg = bias_all[t * 256 + 128 + d],
                        bov = bias_all[t * 256 + 192 + d];
#pragma unroll
            for (int r = 0; r < 4; ++r) {
                const float ai = acc[0][r] + bi, af = acc[1][r] + bf,
                            ag = acc[2][r] + bg, ao = acc[3][r] + bov;
                const float c2 = fmaf(sigm(af), ccr[q][r], sigm(ai) * tanh_fast(ag));
                ccr[q][r] = c2;
                const float h2 = sigm(ao) * tanh_fast(c2);
                const int row = 4 * g4 + r;
                t_lds[wave][row][swz(row, 16 * q + c)] = f2b(h2);
                if (lastt) {
                    const int n = nb + row;
                    chf[n * 64 + d] = h2;
                    ccf[n * 64 + d] = c2;
                }
            }
        }
        ach0 = *(const bf16x8*)(&t_lds[wave][c][swz(c, g4 * 8)]);       // ch(t)
        ach1 = *(const bf16x8*)(&t_lds[wave][c][swz(c, 32 + g4 * 8)]);

        {
            f32x4 oa = (f32x4){0.f, 0.f, 0.f, 0.f};
            oa = __builtin_amdgcn_mfma_f32_16x16x32_bf16(ach0, woB0, oa, 0, 0, 0);
            oa = __builtin_amdgcn_mfma_f32_16x16x32_bf16(ach1, woB1, oa, 0, 0, 0);
            if (c < OUTx) {
                float* outp = out0 + (size_t)t * Nx * OUTx;
#pragma unroll
                for (int r = 0; r < 4; ++r)
                    outp[(nb + 4 * g4 + r) * OUTx + c] = oa[r] + bo_c;
            }
        }
    }
}

// ---------------- C (fallback): graph recompute + cell (round-11) ---------
__global__ __launch_bounds__(TPBF, 2) void k_cell_rc(
    const float* __restrict__ input,
    const float* __restrict__ gh0, const float* __restrict__ gc0,
    const float* __restrict__ ch0, const float* __restrict__ cc0,
    const float* __restrict__ Wge, const float* __restrict__ bge,
    const ushort* __restrict__ Wg, const float* __restrict__ bsum_g,
    const float* __restrict__ Wdy, const float* __restrict__ bdy,
    const ushort* __restrict__ Wc, const float* __restrict__ bias_all,
    const ushort* __restrict__ WoB, const float* __restrict__ bo5,
    float* __restrict__ out0,
    float* __restrict__ chf, float* __restrict__ ccf)
{
    const int tid = threadIdx.x;
    const int wave = tid >> 6, lane = tid & 63;
    const int c = lane & 15, g4 = lane >> 4;
    const int nb = blockIdx.x * 128 + wave * 16;
    const int na = nb + c;

    __shared__ __align__(16) ushort lWg[256 * LWG];
    __shared__ __align__(16) ushort lWc[256 * LWC];
    __shared__ __align__(16) ushort t_lds[8][16][72];

    {
        const uint* src = (const uint*)Wg;
        uint* dst = (uint*)lWg;
        for (int i = tid; i < 256 * (KG / 2); i += TPBF)
            dst[(i / (KG / 2)) * (LWG / 2) + (i % (KG / 2))] = src[i];
        const uint* src2 = (const uint*)Wc;
        uint* dst2 = (uint*)lWc;
        for (int i = tid; i < 256 * (KC / 2); i += TPBF)
            dst2[(i / (KC / 2)) * (LWC / 2) + (i % (KC / 2))] = src2[i];
    }
    __syncthreads();

    float gcr[4][4], ccr[4][4];
#pragma unroll
    for (int q = 0; q < 4; ++q)
#pragma unroll
        for (int r = 0; r < 4; ++r) {
            const int n = nb + 4 * g4 + r, d = 16 * q + c;
            gcr[q][r] = gc0[n * 64 + d];
            ccr[q][r] = cc0[n * 64 + d];
        }
    bf16x8 agh0, agh1, ach0, ach1;
#pragma unroll
    for (int j = 0; j < 8; ++j) {
        agh0[j] = (short)f2b(gh0[na * 64 + g4 * 8 + j]);
        agh1[j] = (short)f2b(gh0[na * 64 + 32 + g4 * 8 + j]);
        ach0[j] = (short)f2b(ch0[na * 64 + g4 * 8 + j]);
        ach1[j] = (short)f2b(ch0[na * 64 + 32 + g4 * 8 + j]);
    }
    bf16x8 woB0 = *(const bf16x8*)(WoB + c * 64 + g4 * 8);
    bf16x8 woB1 = *(const bf16x8*)(WoB + c * 64 + 32 + g4 * 8);
    const float bo_c = (c < OUTx) ? bo5[c] : 0.f;

#pragma unroll 1
    for (int t = 0; t < Sx; ++t) {
        const float* frame = input + (size_t)t * Nx * 2;
        const float f0 = frame[2 * na], f1 = frame[2 * na + 1];
        const int lastt = (t == Sx - 1);

        bf16x8 a0;
#pragma unroll
        for (int j = 0; j < 8; ++j) {
            const int k = g4 * 8 + j;
            float v = fmaf(f1, Wge[2 * k + 1], fmaf(f0, Wge[2 * k], bge[k]));
            a0[j] = (short)f2b(fmaxf(v, 0.f));
        }
#pragma unroll 1
        for (int q = 0; q < 4; ++q) {
            f32x4 acc[4];
#pragma unroll
            for (int g = 0; g < 4; ++g) {
                acc[g] = (f32x4){0.f, 0.f, 0.f, 0.f};
                const ushort* wp = lWg + (16 * (4 * g + q) + c) * LWG + g4 * 8;
                bf16x8 b0 = *(const bf16x8*)(wp);
                bf16x8 b1 = *(const bf16x8*)(wp + 32);
                bf16x8 b2 = *(const bf16x8*)(wp + 64);
                acc[g] = __builtin_amdgcn_mfma_f32_16x16x32_bf16(a0,   b0, acc[g], 0, 0, 0);
                acc[g] = __builtin_amdgcn_mfma_f32_16x16x32_bf16(agh0, b1, acc[g], 0, 0, 0);
                acc[g] = __builtin_amdgcn_mfma_f32_16x16x32_bf16(agh1, b2, acc[g], 0, 0, 0);
            }
            const int d = 16 * q + c;
            const float bi = bsum_g[d], bf = bsum_g[64 + d],
                        bg = bsum_g[128 + d], bo = bsum_g[192 + d];
#pragma unroll
            for (int r = 0; r < 4; ++r) {
                const float ai = acc[0][r] + bi, af = acc[1][r] + bf,
                            ag = acc[2][r] + bg, ao = acc[3][r] + bo;
                const float c2 = fmaf(sigm(af), gcr[q][r], sigm(ai) * tanh_fast(ag));
                gcr[q][r] = c2;
                const float h2 = sigm(ao) * tanh_fast(c2);
                t_lds[wave][4 * g4 + r][16 * q + c] = f2b(h2);
            }
        }
        agh0 = *(const bf16x8*)(&t_lds[wave][c][g4 * 8]);
        agh1 = *(const bf16x8*)(&t_lds[wave][c][32 + g4 * 8]);

        bf16x8 a0c;
#pragma unroll
        for (int j = 0; j < 8; ++j) {
            const int k = g4 * 8 + j;
            float v = fmaf(f1, Wdy[2 * k + 1], fmaf(f0, Wdy[2 * k], bdy[k]));
            a0c[j] = (short)f2b(fmaxf(v, 0.f));
        }
#pragma unroll 1
        for (int q = 0; q < 4; ++q) {
            f32x4 acc[4];
#pragma unroll
            for (int g = 0; g < 4; ++g) {
                acc[g] = (f32x4){0.f, 0.f, 0.f, 0.f};
                const ushort* wp = lWc + (16 * (4 * g + q) + c) * LWC + g4 * 8;
                bf16x8 b0 = *(const bf16x8*)(wp);
                bf16x8 b1 = *(const bf16x8*)(wp + 32);
                bf16x8 b2 = *(const bf16x8*)(wp + 64);
                bf16x8 b3 = *(const bf16x8*)(wp + 96);
                bf16x8 b4 = *(const bf16x8*)(wp + 128);
                acc[g] = __builtin_amdgcn_mfma_f32_16x16x32_bf16(a0c,  b0, acc[g], 0, 0, 0);
                acc[g] = __builtin_amdgcn_mfma_f32_16x16x32_bf16(agh0, b1, acc[g], 0, 0, 0);
                acc[g] = __builtin_amdgcn_mfma_f32_16x16x32_bf16(agh1, b2, acc[g], 0, 0, 0);
                acc[g] = __builtin_amdgcn_mfma_f32_16x16x32_bf16(ach0, b3, acc[g], 0, 0, 0);
                acc[g] = __builtin_amdgcn_mfma_f32_16x16x32_bf16(ach1, b4, acc[g], 0, 0, 0);
            }
            const int d = 16 * q + c;
            const float bi = bias_all[t * 256 + d],
                        bf = bias_all[t * 256 + 64 + d],
                        bg = bias_all[t * 256 + 128 + d],
                        bov = bias_all[t * 256 + 192 + d];
#pragma unroll
            for (int r = 0; r < 4; ++r) {
                const float ai = acc[0][r] + bi, af = acc[1][r] + bf,
                            ag = acc[2][r] + bg, ao = acc[3][r] + bov;
                const float c2 = fmaf(sigm(af), ccr[q][r], sigm(ai) * tanh_fast(ag));
                ccr[q][r] = c2;
                const float h2 = sigm(ao) * tanh_fast(c2);
                t_lds[wave][4 * g4 + r][16 * q + c] = f2b(h2);
                if (lastt) {
                    const int n = nb + 4 * g4 + r;
                    chf[n * 64 + d] = h2;
                    ccf[n * 64 + d] = c2;
                }
            }
        }
        ach0 = *(const bf16x8*)(&t_lds[wave][c][g4 * 8]);
        ach1 = *(const bf16x8*)(&t_lds[wave][c][32 + g4 * 8]);

        {
            f32x4 oa = (f32x4){0.f, 0.f, 0.f, 0.f};
            oa = __builtin_amdgcn_mfma_f32_16x16x32_bf16(ach0, woB0, oa, 0, 0, 0);
            oa = __builtin_amdgcn_mfma_f32_16x16x32_bf16(ach1, woB1, oa, 0, 0, 0);
            if (c < OUTx) {
                float* outp = out0 + (size_t)t * Nx * OUTx;
#pragma unroll
                for (int r = 0; r < 4; ++r)
                    outp[(nb + 4 * g4 + r) * OUTx + c] = oa[r] + bo_c;
            }
        }
    }
}

extern "C" void kernel_launch(void* const* d_in, const int* in_sizes, int n_in,
                              void* d_out, int out_size, void* d_ws, size_t ws_size,
                              hipStream_t stream) {
    const float* input   = (const float*)d_in[0];   // [S][N][2]
    const float* cell_h0 = (const float*)d_in[1];
    const float* cell_c0 = (const float*)d_in[2];
    const float* graph_h0= (const float*)d_in[3];
    const float* graph_c0= (const float*)d_in[4];
    const float* W_dyn   = (const float*)d_in[5];
    const float* b_dyn   = (const float*)d_in[6];
    const float* W_gemb  = (const float*)d_in[7];
    const float* b_gemb  = (const float*)d_in[8];
    const float* Wih_g   = (const float*)d_in[9];
    const float* Whh_g   = (const float*)d_in[10];
    const float* bih_g   = (const float*)d_in[11];
    const float* bhh_g   = (const float*)d_in[12];
    const float* w_graph = (const float*)d_in[13];
    const float* Wih_c   = (const float*)d_in[14];
    const float* Whh_c   = (const float*)d_in[15];
    const float* bih_c   = (const float*)d_in[16];
    const float* bhh_c   = (const float*)d_in[17];
    const float* W_out   = (const float*)d_in[18];
    const float* b_out   = (const float*)d_in[19];

    float* out0 = (float*)d_out;                        // [S][N][5]
    float* chf = out0 + (size_t)Sx * Nx * OUTx;         // [N][64]
    float* ccf = chf + (size_t)Nx * 64;
    float* ghf = ccf + (size_t)Nx * 64;
    float* gcf = ghf + (size_t)Nx * 64;

    size_t off = 0;
    char* base = (char*)d_ws;
    float*  partials= (float*)(base + off); off += (size_t)Sx * GRIDA * 64 * 4;
    float*  bias_all= (float*)(base + off); off += (size_t)Sx * 256 * 4;
    ushort* Wg      = (ushort*)(base + off); off += 256 * KG * 2;
    ushort* Wc      = (ushort*)(base + off); off += 256 * KC * 2;
    ushort* WoB     = (ushort*)(base + off); off += 16 * 64 * 2;
    float*  Wfold2  = (float*)(base + off); off += 64 * 256 * 4;
    float*  bsum_g  = (float*)(base + off); off += 256 * 4;
    float*  bC0     = (float*)(base + off); off += 256 * 4;
    off = (off + 255) & ~(size_t)255;
    const size_t ghb_bytes = (size_t)Sx * Nx * 64 * 2;   // 256 MB
    const bool use_pt = (ws_size >= off + ghb_bytes);
    ushort* ghb = use_pt ? (ushort*)(base + off) : (ushort*)nullptr;

    k_prep<<<64, 256, 0, stream>>>(Wih_g, Whh_g, bih_g, bhh_g, w_graph,
                                   Wih_c, Whh_c, bih_c, bhh_c, W_out,
                                   Wg, Wc, WoB, Wfold2, bsum_g, bC0);

    k_graph_all<<<GRIDA, TPB, 0, stream>>>(input, graph_h0, graph_c0,
                                           W_gemb, b_gemb, Wg, bsum_g,
                                           partials, ghb, ghf, gcf);

    k_bias<<<Sx, 256, 0, stream>>>(partials, Wfold2, bC0, bias_all);

    if (use_pt) {
        k_cell_pt<<<GRIDA, TPB, 0, stream>>>(input, ghb, cell_h0, cell_c0,
                                             W_dyn, b_dyn, Wc, bias_all,
                                             WoB, b_out, out0, chf, ccf);
    } else {
        k_cell_rc<<<GRIDF, TPBF, 0, stream>>>(input, graph_h0, graph_c0,
                                              cell_h0, cell_c0,
                                              W_gemb, b_gemb, Wg, bsum_g,
                                              W_dyn, b_dyn, Wc, bias_all,
                                              WoB, b_out, out0, chf, ccf);
    }
}

// Round 14
// 585.563 us; speedup vs baseline: 7.3007x; 1.0157x over previous
//
#include <hip/hip_runtime.h>
#include <hip/hip_bf16.h>

// GraphLSTM v10 = round-13 + VALU trims on the now-dominant k_graph_all.
// Round-13 counters: A 330us VALUBusy 62% MfmaUtil 13% occ 47% FETCH 25MB.
// 1) A: q-loop unroll 2 (VGPR 56 of 128 cap -> headroom; spills would show
//    as FETCH explosion), bsum_g hoisted to 16 regs (step-invariant).
// 2) A+C: input-projection fragments built with native __float2bfloat16
//    (RNE, bit-identical) so compiler can pair v_cvt_pk_bf16_f32 (m240).
// C kept at unroll 1 (tighter liveness; round-9 spill lesson).

#define Sx    32
#define Nx    65536
#define OUTx  5
#define KG    96              // graph gates K: [gemb(32) | gh(64)]
#define KC    160             // cell gates K:  [dyn(32) | gh(64) | ch(64)]
#define LWG   104             // lds row stride (ushorts) for Wg (96+8 pad)
#define LWC   168             // lds row stride (ushorts) for Wc (160+8 pad)
#define GRIDA 256             // blocks for A and C-pt (16 waves each)
#define TPB   1024            // 16 waves x 16 nodes = 256 nodes/block
#define GRIDF 512             // fallback k_cell_rc geometry (8 waves)
#define TPBF  512

typedef __attribute__((ext_vector_type(4))) float f32x4;
typedef __attribute__((ext_vector_type(8))) short bf16x8;
typedef unsigned short ushort;
typedef unsigned int uint;

__device__ __forceinline__ float sigm(float x) {
    return __builtin_amdgcn_rcpf(1.f + __expf(-x));
}
__device__ __forceinline__ float tanh_fast(float x) {
    return fmaf(-2.f, __builtin_amdgcn_rcpf(1.f + __expf(2.f * x)), 1.f);
}
__device__ __forceinline__ ushort f2b(float x) {
    uint u = __float_as_uint(x);
    u += 0x7fffu + ((u >> 16) & 1u);   // RNE
    return (ushort)(u >> 16);
}
// native cast (RNE, pairable into v_cvt_pk_bf16_f32 by the compiler)
__device__ __forceinline__ ushort f2b_n(float x) {
    __hip_bfloat16 b = __float2bfloat16(x);
    return *reinterpret_cast<ushort*>(&b);
}
// transpose-tile swizzle: store logical (row,col) at col'(row,col).
__device__ __forceinline__ int swz(int row, int col) {
    return col ^ (((row >> 2) & 3) << 4);
}

// ---------------- weight prep (once per launch, parallel) ----------------
__global__ __launch_bounds__(256) void k_prep(
    const float* __restrict__ Wih_g, const float* __restrict__ Whh_g,
    const float* __restrict__ bih_g, const float* __restrict__ bhh_g,
    const float* __restrict__ wgr,
    const float* __restrict__ Wih_c, const float* __restrict__ Whh_c,
    const float* __restrict__ bih_c, const float* __restrict__ bhh_c,
    const float* __restrict__ Wout,
    ushort* __restrict__ Wg, ushort* __restrict__ Wc,
    ushort* __restrict__ WoB,
    float* __restrict__ Wfold2,
    float* __restrict__ bsum_g, float* __restrict__ bC0)
{
    const int tid = blockIdx.x * 256 + threadIdx.x;
    const int nt = gridDim.x * 256;
    for (int idx = tid; idx < 256 * KG; idx += nt) {
        int col = idx / KG, k = idx % KG;
        float v = (k < 32) ? Wih_g[col * 32 + k] : Whh_g[col * 64 + (k - 32)];
        Wg[idx] = f2b(v);
    }
    for (int idx = tid; idx < 256 * KC; idx += nt) {
        int col = idx / KC, k = idx % KC;
        float v;
        if (k < 32) v = Wih_c[col * 64 + k];
        else if (k < 96) {
            int d = k - 32; float a = 0.f;
            for (int j = 0; j < 32; ++j)
                a = fmaf(wgr[d * 32 + j], Wih_c[col * 64 + 32 + j], a);
            v = -a;   // per-node part of loo is (-gh)
        } else v = Whh_c[col * 64 + (k - 96)];
        Wc[idx] = f2b(v);
    }
    for (int idx = tid; idx < 16 * 64; idx += nt) {
        int col = idx >> 6, k = idx & 63;
        WoB[idx] = (col < OUTx) ? f2b(Wout[col * 64 + k]) : (ushort)0;
    }
    for (int idx = tid; idx < 64 * 256; idx += nt) {
        int k = idx >> 8, col = idx & 255;
        float a = 0.f;
        for (int j = 0; j < 32; ++j)
            a = fmaf(wgr[k * 32 + j], Wih_c[col * 64 + 32 + j], a);
        Wfold2[idx] = a;
    }
    if (tid < 256) {
        bsum_g[tid] = bih_g[tid] + bhh_g[tid];
        bC0[tid]    = bih_c[tid] + bhh_c[tid];
    }
}

// ---------------- A: graph LSTM, all steps -------------------------------
__global__ __launch_bounds__(TPB, 2) void k_graph_all(
    const float* __restrict__ input,               // [S][N][2]
    const float* __restrict__ gh0, const float* __restrict__ gc0,
    const float* __restrict__ Wge, const float* __restrict__ bge,
    const ushort* __restrict__ Wg, const float* __restrict__ bsum_g,
    float* __restrict__ partials,                  // [S][GRIDA][64]
    ushort* __restrict__ ghb,                      // [S][N][64] or null
    float* __restrict__ ghf, float* __restrict__ gcf)
{
    const int tid = threadIdx.x;
    const int wave = tid >> 6, lane = tid & 63;
    const int c = lane & 15, g4 = lane >> 4;
    const int nb = blockIdx.x * 256 + wave * 16;
    const int na = nb + c;

    __shared__ __align__(16) ushort lWg[256 * LWG];      // 53.2 KB
    __shared__ __align__(16) ushort t_lds[16][16][72];   // 36.9 KB
    __shared__ float wsum[2][16][64];                    //  8.2 KB

    {
        const uint* src = (const uint*)Wg;
        uint* dst = (uint*)lWg;
        for (int i = tid; i < 256 * (KG / 2); i += TPB)
            dst[(i / (KG / 2)) * (LWG / 2) + (i % (KG / 2))] = src[i];
    }
    __syncthreads();

    // hoist step-invariant biases: 16 regs (4 gates x 4 q), d = 16q+c
    float bsg[4][4];
#pragma unroll
    for (int q = 0; q < 4; ++q)
#pragma unroll
        for (int g = 0; g < 4; ++g)
            bsg[q][g] = bsum_g[64 * g + 16 * q + c];

    float gcr[4][4];
#pragma unroll
    for (int q = 0; q < 4; ++q)
#pragma unroll
        for (int r = 0; r < 4; ++r)
            gcr[q][r] = gc0[(nb + 4 * g4 + r) * 64 + 16 * q + c];
    bf16x8 agh0, agh1;
#pragma unroll
    for (int j = 0; j < 8; ++j) {
        agh0[j] = (short)f2b(gh0[na * 64 + g4 * 8 + j]);
        agh1[j] = (short)f2b(gh0[na * 64 + 32 + g4 * 8 + j]);
    }

#pragma unroll 1
    for (int t = 0; t < Sx; ++t) {
        const float* frame = input + (size_t)t * Nx * 2;
        const float f0 = frame[2 * na], f1 = frame[2 * na + 1];
        const int lastt = (t == Sx - 1);
        bf16x8 a0;
#pragma unroll
        for (int j = 0; j < 8; ++j) {
            const int k = g4 * 8 + j;
            float v = fmaf(f1, Wge[2 * k + 1], fmaf(f0, Wge[2 * k], bge[k]));
            a0[j] = (short)f2b_n(fmaxf(v, 0.f));
        }
        float hsq[4];
#pragma unroll 2
        for (int q = 0; q < 4; ++q) {
            f32x4 acc[4];
#pragma unroll
            for (int g = 0; g < 4; ++g) {
                acc[g] = (f32x4){0.f, 0.f, 0.f, 0.f};
                const ushort* wp = lWg + (16 * (4 * g + q) + c) * LWG + g4 * 8;
                bf16x8 b0 = *(const bf16x8*)(wp);
                bf16x8 b1 = *(const bf16x8*)(wp + 32);
                bf16x8 b2 = *(const bf16x8*)(wp + 64);
                acc[g] = __builtin_amdgcn_mfma_f32_16x16x32_bf16(a0,   b0, acc[g], 0, 0, 0);
                acc[g] = __builtin_amdgcn_mfma_f32_16x16x32_bf16(agh0, b1, acc[g], 0, 0, 0);
                acc[g] = __builtin_amdgcn_mfma_f32_16x16x32_bf16(agh1, b2, acc[g], 0, 0, 0);
            }
            const int d = 16 * q + c;
            float s_r = 0.f;
#pragma unroll
            for (int r = 0; r < 4; ++r) {
                const float ai = acc[0][r] + bsg[q][0], af = acc[1][r] + bsg[q][1],
                            ag = acc[2][r] + bsg[q][2], ao = acc[3][r] + bsg[q][3];
                const float c2 = fmaf(sigm(af), gcr[q][r], sigm(ai) * tanh_fast(ag));
                gcr[q][r] = c2;
                const float h2 = sigm(ao) * tanh_fast(c2);
                const int row = 4 * g4 + r;
                t_lds[wave][row][swz(row, 16 * q + c)] = f2b(h2);
                if (lastt) {
                    const int n = nb + row;
                    ghf[n * 64 + d] = h2;
                    gcf[n * 64 + d] = c2;
                }
                s_r += h2;
            }
            hsq[q] = s_r;
        }
#pragma unroll
        for (int q = 0; q < 4; ++q) {
            float v = hsq[q];
            v += __shfl_xor(v, 16);
            v += __shfl_xor(v, 32);
            hsq[q] = v;
        }
        if (g4 == 0) {
#pragma unroll
            for (int q = 0; q < 4; ++q) wsum[t & 1][wave][16 * q + c] = hsq[q];
        }
        __syncthreads();          // wsum visible (t_lds is same-wave only)
        agh0 = *(const bf16x8*)(&t_lds[wave][c][swz(c, g4 * 8)]);
        agh1 = *(const bf16x8*)(&t_lds[wave][c][swz(c, 32 + g4 * 8)]);
        if (ghb) {   // publish gh(t): [N][64] layout, coalesced 16B stores
            ushort* gp = ghb + ((size_t)t * Nx + na) * 64 + g4 * 8;
            *(bf16x8*)(gp)      = agh0;
            *(bf16x8*)(gp + 32) = agh1;
        }
        if (tid < 64) {
            float a = 0.f;
#pragma unroll
            for (int w8 = 0; w8 < 16; ++w8) a += wsum[t & 1][w8][tid];
            partials[((size_t)t * GRIDA + blockIdx.x) * 64 + tid] = a;
        }
    }
}

// ---------------- B: per-step bias from partials ---------------------------
__global__ __launch_bounds__(256) void k_bias(
    const float* __restrict__ partials,   // [S][GRIDA][64]
    const float* __restrict__ Wfold2, const float* __restrict__ bC0,
    float* __restrict__ bias_all)         // [S][256]
{
    const int t = blockIdx.x, tid = threadIdx.x;
    __shared__ float red[4][64];
    __shared__ float S[64];
    const int d = tid & 63, j = tid >> 6;
    float a = 0.f;
    for (int b = j; b < GRIDA; b += 4)
        a += partials[((size_t)t * GRIDA + b) * 64 + d];
    red[j][d] = a;
    __syncthreads();
    if (tid < 64) S[tid] = red[0][tid] + red[1][tid] + red[2][tid] + red[3][tid];
    __syncthreads();
    float bv = bC0[tid];
#pragma unroll
    for (int k = 0; k < 64; ++k) bv = fmaf(S[k], Wfold2[k * 256 + tid], bv);
    bias_all[t * 256 + tid] = bv;
}

// ---------------- C (pass-through): cell LSTM only ------------------------
__global__ __launch_bounds__(TPB, 2) void k_cell_pt(
    const float* __restrict__ input,               // [S][N][2]
    const ushort* __restrict__ ghb,                // [S][N][64]
    const float* __restrict__ ch0, const float* __restrict__ cc0,
    const float* __restrict__ Wdy, const float* __restrict__ bdy,
    const ushort* __restrict__ Wc, const float* __restrict__ bias_all,
    const ushort* __restrict__ WoB, const float* __restrict__ bo5,
    float* __restrict__ out0,                      // [S][N][5]
    float* __restrict__ chf, float* __restrict__ ccf)
{
    const int tid = threadIdx.x;
    const int wave = tid >> 6, lane = tid & 63;
    const int c = lane & 15, g4 = lane >> 4;
    const int nb = blockIdx.x * 256 + wave * 16;
    const int na = nb + c;

    __shared__ __align__(16) ushort lWc[256 * LWC];      // 86 KB
    __shared__ __align__(16) ushort t_lds[16][16][72];   // 36.9 KB

    {
        const uint* src2 = (const uint*)Wc;
        uint* dst2 = (uint*)lWc;
        for (int i = tid; i < 256 * (KC / 2); i += TPB)
            dst2[(i / (KC / 2)) * (LWC / 2) + (i % (KC / 2))] = src2[i];
    }
    __syncthreads();

    float ccr[4][4];
#pragma unroll
    for (int q = 0; q < 4; ++q)
#pragma unroll
        for (int r = 0; r < 4; ++r)
            ccr[q][r] = cc0[(nb + 4 * g4 + r) * 64 + 16 * q + c];
    bf16x8 ach0, ach1;
#pragma unroll
    for (int j = 0; j < 8; ++j) {
        ach0[j] = (short)f2b(ch0[na * 64 + g4 * 8 + j]);
        ach1[j] = (short)f2b(ch0[na * 64 + 32 + g4 * 8 + j]);
    }
    bf16x8 woB0 = *(const bf16x8*)(WoB + c * 64 + g4 * 8);
    bf16x8 woB1 = *(const bf16x8*)(WoB + c * 64 + 32 + g4 * 8);
    const float bo_c = (c < OUTx) ? bo5[c] : 0.f;

#pragma unroll 1
    for (int t = 0; t < Sx; ++t) {
        const float* frame = input + (size_t)t * Nx * 2;
        const float f0 = frame[2 * na], f1 = frame[2 * na + 1];
        const int lastt = (t == Sx - 1);

        // gh(t) from A (same bits the recompute would produce)
        const ushort* gp = ghb + ((size_t)t * Nx + na) * 64 + g4 * 8;
        bf16x8 agh0 = *(const bf16x8*)(gp);
        bf16x8 agh1 = *(const bf16x8*)(gp + 32);

        bf16x8 a0c;
#pragma unroll
        for (int j = 0; j < 8; ++j) {
            const int k = g4 * 8 + j;
            float v = fmaf(f1, Wdy[2 * k + 1], fmaf(f0, Wdy[2 * k], bdy[k]));
            a0c[j] = (short)f2b_n(fmaxf(v, 0.f));
        }
#pragma unroll 1
        for (int q = 0; q < 4; ++q) {
            f32x4 acc[4];
#pragma unroll
            for (int g = 0; g < 4; ++g) {
                acc[g] = (f32x4){0.f, 0.f, 0.f, 0.f};
                const ushort* wp = lWc + (16 * (4 * g + q) + c) * LWC + g4 * 8;
                bf16x8 b0 = *(const bf16x8*)(wp);
                bf16x8 b1 = *(const bf16x8*)(wp + 32);
                bf16x8 b2 = *(const bf16x8*)(wp + 64);
                bf16x8 b3 = *(const bf16x8*)(wp + 96);
                bf16x8 b4 = *(const bf16x8*)(wp + 128);
                acc[g] = __builtin_amdgcn_mfma_f32_16x16x32_bf16(a0c,  b0, acc[g], 0, 0, 0);
                acc[g] = __builtin_amdgcn_mfma_f32_16x16x32_bf16(agh0, b1, acc[g], 0, 0, 0);
                acc[g] = __builtin_amdgcn_mfma_f32_16x16x32_bf16(agh1, b2, acc[g], 0, 0, 0);
                acc[g] = __builtin_amdgcn_mfma_f32_16x16x32_bf16(ach0, b3, acc[g], 0, 0, 0);
                acc[g] = __builtin_amdgcn_mfma_f32_16x16x32_bf16(ach1, b4, acc[g], 0, 0, 0);
            }
            const int d = 16 * q + c;
            const float bi = bias_all[t * 256 + d],
                        bf = bias_all[t * 256 + 64 + d],
                        bg = bias_all[t * 256 + 128 + d],
                        bov = bias_all[t * 256 + 192 + d];
#pragma unroll
            for (int r = 0; r < 4; ++r) {
                const float ai = acc[0][r] + bi, af = acc[1][r] + bf,
                            ag = acc[2][r] + bg, ao = acc[3][r] + bov;
                const float c2 = fmaf(sigm(af), ccr[q][r], sigm(ai) * tanh_fast(ag));
                ccr[q][r] = c2;
                const float h2 = sigm(ao) * tanh_fast(c2);
                const int row = 4 * g4 + r;
                t_lds[wave][row][swz(row, 16 * q + c)] = f2b(h2);
                if (lastt) {
                    const int n = nb + row;
                    chf[n * 64 + d] = h2;
                    ccf[n * 64 + d] = c2;
                }
            }
        }
        ach0 = *(const bf16x8*)(&t_lds[wave][c][swz(c, g4 * 8)]);       // ch(t)
        ach1 = *(const bf16x8*)(&t_lds[wave][c][swz(c, 32 + g4 * 8)]);

        {
            f32x4 oa = (f32x4){0.f, 0.f, 0.f, 0.f};
            oa = __builtin_amdgcn_mfma_f32_16x16x32_bf16(ach0, woB0, oa, 0, 0, 0);
            oa = __builtin_amdgcn_mfma_f32_16x16x32_bf16(ach1, woB1, oa, 0, 0, 0);
            if (c < OUTx) {
                float* outp = out0 + (size_t)t * Nx * OUTx;
#pragma unroll
                for (int r = 0; r < 4; ++r)
                    outp[(nb + 4 * g4 + r) * OUTx + c] = oa[r] + bo_c;
            }
        }
    }
}

// ---------------- C (fallback): graph recompute + cell (round-11) ---------
__global__ __launch_bounds__(TPBF, 2) void k_cell_rc(
    const float* __restrict__ input,
    const float* __restrict__ gh0, const float* __restrict__ gc0,
    const float* __restrict__ ch0, const float* __restrict__ cc0,
    const float* __restrict__ Wge, const float* __restrict__ bge,
    const ushort* __restrict__ Wg, const float* __restrict__ bsum_g,
    const float* __restrict__ Wdy, const float* __restrict__ bdy,
    const ushort* __restrict__ Wc, const float* __restrict__ bias_all,
    const ushort* __restrict__ WoB, const float* __restrict__ bo5,
    float* __restrict__ out0,
    float* __restrict__ chf, float* __restrict__ ccf)
{
    const int tid = threadIdx.x;
    const int wave = tid >> 6, lane = tid & 63;
    const int c = lane & 15, g4 = lane >> 4;
    const int nb = blockIdx.x * 128 + wave * 16;
    const int na = nb + c;

    __shared__ __align__(16) ushort lWg[256 * LWG];
    __shared__ __align__(16) ushort lWc[256 * LWC];
    __shared__ __align__(16) ushort t_lds[8][16][72];

    {
        const uint* src = (const uint*)Wg;
        uint* dst = (uint*)lWg;
        for (int i = tid; i < 256 * (KG / 2); i += TPBF)
            dst[(i / (KG / 2)) * (LWG / 2) + (i % (KG / 2))] = src[i];
        const uint* src2 = (const uint*)Wc;
        uint* dst2 = (uint*)lWc;
        for (int i = tid; i < 256 * (KC / 2); i += TPBF)
            dst2[(i / (KC / 2)) * (LWC / 2) + (i % (KC / 2))] = src2[i];
    }
    __syncthreads();

    float gcr[4][4], ccr[4][4];
#pragma unroll
    for (int q = 0; q < 4; ++q)
#pragma unroll
        for (int r = 0; r < 4; ++r) {
            const int n = nb + 4 * g4 + r, d = 16 * q + c;
            gcr[q][r] = gc0[n * 64 + d];
            ccr[q][r] = cc0[n * 64 + d];
        }
    bf16x8 agh0, agh1, ach0, ach1;
#pragma unroll
    for (int j = 0; j < 8; ++j) {
        agh0[j] = (short)f2b(gh0[na * 64 + g4 * 8 + j]);
        agh1[j] = (short)f2b(gh0[na * 64 + 32 + g4 * 8 + j]);
        ach0[j] = (short)f2b(ch0[na * 64 + g4 * 8 + j]);
        ach1[j] = (short)f2b(ch0[na * 64 + 32 + g4 * 8 + j]);
    }
    bf16x8 woB0 = *(const bf16x8*)(WoB + c * 64 + g4 * 8);
    bf16x8 woB1 = *(const bf16x8*)(WoB + c * 64 + 32 + g4 * 8);
    const float bo_c = (c < OUTx) ? bo5[c] : 0.f;

#pragma unroll 1
    for (int t = 0; t < Sx; ++t) {
        const float* frame = input + (size_t)t * Nx * 2;
        const float f0 = frame[2 * na], f1 = frame[2 * na + 1];
        const int lastt = (t == Sx - 1);

        bf16x8 a0;
#pragma unroll
        for (int j = 0; j < 8; ++j) {
            const int k = g4 * 8 + j;
            float v = fmaf(f1, Wge[2 * k + 1], fmaf(f0, Wge[2 * k], bge[k]));
            a0[j] = (short)f2b(fmaxf(v, 0.f));
        }
#pragma unroll 1
        for (int q = 0; q < 4; ++q) {
            f32x4 acc[4];
#pragma unroll
            for (int g = 0; g < 4; ++g) {
                acc[g] = (f32x4){0.f, 0.f, 0.f, 0.f};
                const ushort* wp = lWg + (16 * (4 * g + q) + c) * LWG + g4 * 8;
                bf16x8 b0 = *(const bf16x8*)(wp);
                bf16x8 b1 = *(const bf16x8*)(wp + 32);
                bf16x8 b2 = *(const bf16x8*)(wp + 64);
                acc[g] = __builtin_amdgcn_mfma_f32_16x16x32_bf16(a0,   b0, acc[g], 0, 0, 0);
                acc[g] = __builtin_amdgcn_mfma_f32_16x16x32_bf16(agh0, b1, acc[g], 0, 0, 0);
                acc[g] = __builtin_amdgcn_mfma_f32_16x16x32_bf16(agh1, b2, acc[g], 0, 0, 0);
            }
            const int d = 16 * q + c;
            const float bi = bsum_g[d], bf = bsum_g[64 + d],
                        bg = bsum_g[128 + d], bo = bsum_g[192 + d];
#pragma unroll
            for (int r = 0; r < 4; ++r) {
                const float ai = acc[0][r] + bi, af = acc[1][r] + bf,
                            ag = acc[2][r] + bg, ao = acc[3][r] + bo;
                const float c2 = fmaf(sigm(af), gcr[q][r], sigm(ai) * tanh_fast(ag));
                gcr[q][r] = c2;
                const float h2 = sigm(ao) * tanh_fast(c2);
                t_lds[wave][4 * g4 + r][16 * q + c] = f2b(h2);
            }
        }
        agh0 = *(const bf16x8*)(&t_lds[wave][c][g4 * 8]);
        agh1 = *(const bf16x8*)(&t_lds[wave][c][32 + g4 * 8]);

        bf16x8 a0c;
#pragma unroll
        for (int j = 0; j < 8; ++j) {
            const int k = g4 * 8 + j;
            float v = fmaf(f1, Wdy[2 * k + 1], fmaf(f0, Wdy[2 * k], bdy[k]));
            a0c[j] = (short)f2b(fmaxf(v, 0.f));
        }
#pragma unroll 1
        for (int q = 0; q < 4; ++q) {
            f32x4 acc[4];
#pragma unroll
            for (int g = 0; g < 4; ++g) {
                acc[g] = (f32x4){0.f, 0.f, 0.f, 0.f};
                const ushort* wp = lWc + (16 * (4 * g + q) + c) * LWC + g4 * 8;
                bf16x8 b0 = *(const bf16x8*)(wp);
                bf16x8 b1 = *(const bf16x8*)(wp + 32);
                bf16x8 b2 = *(const bf16x8*)(wp + 64);
                bf16x8 b3 = *(const bf16x8*)(wp + 96);
                bf16x8 b4 = *(const bf16x8*)(wp + 128);
                acc[g] = __builtin_amdgcn_mfma_f32_16x16x32_bf16(a0c,  b0, acc[g], 0, 0, 0);
                acc[g] = __builtin_amdgcn_mfma_f32_16x16x32_bf16(agh0, b1, acc[g], 0, 0, 0);
                acc[g] = __builtin_amdgcn_mfma_f32_16x16x32_bf16(agh1, b2, acc[g], 0, 0, 0);
                acc[g] = __builtin_amdgcn_mfma_f32_16x16x32_bf16(ach0, b3, acc[g], 0, 0, 0);
                acc[g] = __builtin_amdgcn_mfma_f32_16x16x32_bf16(ach1, b4, acc[g], 0, 0, 0);
            }
            const int d = 16 * q + c;
            const float bi = bias_all[t * 256 + d],
                        bf = bias_all[t * 256 + 64 + d],
                        bg = bias_all[t * 256 + 128 + d],
                        bov = bias_all[t * 256 + 192 + d];
#pragma unroll
            for (int r = 0; r < 4; ++r) {
                const float ai = acc[0][r] + bi, af = acc[1][r] + bf,
                            ag = acc[2][r] + bg, ao = acc[3][r] + bov;
                const float c2 = fmaf(sigm(af), ccr[q][r], sigm(ai) * tanh_fast(ag));
                ccr[q][r] = c2;
                const float h2 = sigm(ao) * tanh_fast(c2);
                t_lds[wave][4 * g4 + r][16 * q + c] = f2b(h2);
                if (lastt) {
                    const int n = nb + 4 * g4 + r;
                    chf[n * 64 + d] = h2;
                    ccf[n * 64 + d] = c2;
                }
            }
        }
        ach0 = *(const bf16x8*)(&t_lds[wave][c][g4 * 8]);
        ach1 = *(const bf16x8*)(&t_lds[wave][c][32 + g4 * 8]);

        {
            f32x4 oa = (f32x4){0.f, 0.f, 0.f, 0.f};
            oa = __builtin_amdgcn_mfma_f32_16x16x32_bf16(ach0, woB0, oa, 0, 0, 0);
            oa = __builtin_amdgcn_mfma_f32_16x16x32_bf16(ach1, woB1, oa, 0, 0, 0);
            if (c < OUTx) {
                float* outp = out0 + (size_t)t * Nx * OUTx;
#pragma unroll
                for (int r = 0; r < 4; ++r)
                    outp[(nb + 4 * g4 + r) * OUTx + c] = oa[r] + bo_c;
            }
        }
    }
}

extern "C" void kernel_launch(void* const* d_in, const int* in_sizes, int n_in,
                              void* d_out, int out_size, void* d_ws, size_t ws_size,
                              hipStream_t stream) {
    const float* input   = (const float*)d_in[0];   // [S][N][2]
    const float* cell_h0 = (const float*)d_in[1];
    const float* cell_c0 = (const float*)d_in[2];
    const float* graph_h0= (const float*)d_in[3];
    const float* graph_c0= (const float*)d_in[4];
    const float* W_dyn   = (const float*)d_in[5];
    const float* b_dyn   = (const float*)d_in[6];
    const float* W_gemb  = (const float*)d_in[7];
    const float* b_gemb  = (const float*)d_in[8];
    const float* Wih_g   = (const float*)d_in[9];
    const float* Whh_g   = (const float*)d_in[10];
    const float* bih_g   = (const float*)d_in[11];
    const float* bhh_g   = (const float*)d_in[12];
    const float* w_graph = (const float*)d_in[13];
    const float* Wih_c   = (const float*)d_in[14];
    const float* Whh_c   = (const float*)d_in[15];
    const float* bih_c   = (const float*)d_in[16];
    const float* bhh_c   = (const float*)d_in[17];
    const float* W_out   = (const float*)d_in[18];
    const float* b_out   = (const float*)d_in[19];

    float* out0 = (float*)d_out;                        // [S][N][5]
    float* chf = out0 + (size_t)Sx * Nx * OUTx;         // [N][64]
    float* ccf = chf + (size_t)Nx * 64;
    float* ghf = ccf + (size_t)Nx * 64;
    float* gcf = ghf + (size_t)Nx * 64;

    size_t off = 0;
    char* base = (char*)d_ws;
    float*  partials= (float*)(base + off); off += (size_t)Sx * GRIDA * 64 * 4;
    float*  bias_all= (float*)(base + off); off += (size_t)Sx * 256 * 4;
    ushort* Wg      = (ushort*)(base + off); off += 256 * KG * 2;
    ushort* Wc      = (ushort*)(base + off); off += 256 * KC * 2;
    ushort* WoB     = (ushort*)(base + off); off += 16 * 64 * 2;
    float*  Wfold2  = (float*)(base + off); off += 64 * 256 * 4;
    float*  bsum_g  = (float*)(base + off); off += 256 * 4;
    float*  bC0     = (float*)(base + off); off += 256 * 4;
    off = (off + 255) & ~(size_t)255;
    const size_t ghb_bytes = (size_t)Sx * Nx * 64 * 2;   // 256 MB
    const bool use_pt = (ws_size >= off + ghb_bytes);
    ushort* ghb = use_pt ? (ushort*)(base + off) : (ushort*)nullptr;

    k_prep<<<64, 256, 0, stream>>>(Wih_g, Whh_g, bih_g, bhh_g, w_graph,
                                   Wih_c, Whh_c, bih_c, bhh_c, W_out,
                                   Wg, Wc, WoB, Wfold2, bsum_g, bC0);

    k_graph_all<<<GRIDA, TPB, 0, stream>>>(input, graph_h0, graph_c0,
                                           W_gemb, b_gemb, Wg, bsum_g,
                                           partials, ghb, ghf, gcf);

    k_bias<<<Sx, 256, 0, stream>>>(partials, Wfold2, bC0, bias_all);

    if (use_pt) {
        k_cell_pt<<<GRIDA, TPB, 0, stream>>>(input, ghb, cell_h0, cell_c0,
                                             W_dyn, b_dyn, Wc, bias_all,
                                             WoB, b_out, out0, chf, ccf);
    } else {
        k_cell_rc<<<GRIDF, TPBF, 0, stream>>>(input, graph_h0, graph_c0,
                                              cell_h0, cell_c0,
                                              W_gemb, b_gemb, Wg, bsum_g,
                                              W_dyn, b_dyn, Wc, bias_all,
                                              WoB, b_out, out0, chf, ccf);
    }
}